// Round 9
// baseline (186.305 us; speedup 1.0000x reference)
//
#include <hip/hip_runtime.h>
#include <math.h>

#define BATCH 32768

typedef unsigned int u32;

#if defined(__has_builtin)
#if __has_builtin(__builtin_amdgcn_permlane32_swap) && __has_builtin(__builtin_amdgcn_permlane16_swap)
#define USE_PERMLANE 1
#else
#define USE_PERMLANE 0
#endif
#else
#define USE_PERMLANE 0
#endif

// ---------------------------------------------------------------------------
// Compile-time circuit derivation (lazy CNOT tracking over GF(2)).
// Physical index p (10 bits): lane = p>>4 (bits 9..4), reg t = p&15.
// One amp = one u32 = packed fp16 {re(lo), im(hi)}.
// Layer 0 folded into the embedding; layers 1..3 are generalized pair-mix
// gates with compile-time partner/select masks.
// ---------------------------------------------------------------------------
struct GateC { unsigned prt, sel; };
struct CircuitT { GateC g[4][10]; unsigned srow[10]; };

constexpr CircuitT make_circuit() {
  CircuitT C{};
  unsigned row[10], col[10];
  for (int b = 0; b < 10; ++b) { row[b] = 1u << b; col[b] = 1u << b; }
  for (int l = 0; l < 4; ++l) {
    for (int w = 0; w < 10; ++w) {
      C.g[l][w].prt = col[9 - w];
      C.g[l][w].sel = row[9 - w];
    }
    const int r = (l % 9) + 1;
    for (int w = 0; w < 10; ++w) {
      const int c = w, t = (w + r) % 10;
      const int bc = 9 - c, bt = 9 - t;
      row[bt] ^= row[bc];
      col[bc] ^= col[bt];
    }
  }
  for (int i = 0; i < 10; ++i) C.srow[i] = row[9 - i];
  return C;
}
constexpr CircuitT CIRC = make_circuit();

// ---------------- cross-lane primitives (u32) ----------------
template<int CTRL>
__device__ __forceinline__ u32 dppu(u32 v) {
  return (u32)__builtin_amdgcn_update_dpp((int)v, (int)v, CTRL, 0xF, 0xF, false);
}

template<int LOW>
__device__ __forceinline__ u32 dpp_low(u32 v) {
  static_assert(LOW >= 0 && LOW <= 15, "bad mask");
  if constexpr (LOW == 0) return v;
  else if constexpr (LOW == 1) return dppu<0xB1>(v);        // quad [1,0,3,2]
  else if constexpr (LOW == 2) return dppu<0x4E>(v);        // quad [2,3,0,1]
  else if constexpr (LOW == 3) return dppu<0x1B>(v);        // quad [3,2,1,0]
  else if constexpr (LOW == 7) return dppu<0x141>(v);       // row_half_mirror
  else if constexpr (LOW == 15) return dppu<0x140>(v);      // row_mirror
  else if constexpr (LOW >= 4 && LOW <= 6) return dpp_low<LOW ^ 7>(dppu<0x141>(v));
  else return dpp_low<LOW ^ 15>(dppu<0x140>(v));            // 8..14
}

constexpr int dpp_ops_low(int low) {
  if (low == 0) return 0;
  if (low == 1 || low == 2 || low == 3 || low == 7 || low == 15) return 1;
  if ((low >= 4 && low <= 6) || low == 8 || (low >= 12 && low <= 14)) return 2;
  return 3;
}
constexpr int chain_cost(int M) {
#if !USE_PERMLANE
  if (M & 48) return 99;
#endif
  return ((M & 32) ? 2 : 0) + ((M & 16) ? 2 : 0) + dpp_ops_low(M & 15);
}
// Pipe rebalance (round 9): VALU chain costs ~0.5 CU-cyc/op vs DS ~2-4.6
// CU-cyc/op -> keep chains up to cost 3 on VALU; DS only for cost >= 4.
constexpr bool use_ds_mask(int M) { return chain_cost(M) >= 4; }

#if USE_PERMLANE
__device__ __forceinline__ u32 xor16u(u32 v, int lane) {
  auto r = __builtin_amdgcn_permlane16_swap(v, v, false, false);
  return (lane & 16) ? r[0] : r[1];
}
__device__ __forceinline__ u32 xor32u(u32 v, int lane) {
  auto r = __builtin_amdgcn_permlane32_swap(v, v, false, false);
  return (lane & 32) ? r[0] : r[1];
}
#else
__device__ __forceinline__ u32 xor16u(u32 v, int lane) { return (u32)__shfl_xor((int)v, 16, 64); }
__device__ __forceinline__ u32 xor32u(u32 v, int lane) { return (u32)__shfl_xor((int)v, 32, 64); }
#endif

template<int M>
__device__ __forceinline__ u32 lshuf(u32 v, int lane, int bpa) {
  if constexpr (use_ds_mask(M)) {
    if constexpr ((M & 32) != 0) {
      return (u32)__builtin_amdgcn_ds_bpermute(bpa, (int)v);
    } else {
      return (u32)__builtin_amdgcn_ds_swizzle((int)v, 0x1F | (M << 10));
    }
  } else {
    u32 t = v;
    if constexpr ((M & 32) != 0) t = xor32u(t, lane);
    if constexpr ((M & 16) != 0) t = xor16u(t, lane);
    if constexpr ((M & 15) != 0) t = dpp_low<M & 15>(t);
    return t;
  }
}

// ---------------- float cross-lane (prenet/epilogue) ----------------
template<int CTRL>
__device__ __forceinline__ float dppf(float v) {
  const int i = __float_as_int(v);
  return __int_as_float(__builtin_amdgcn_update_dpp(i, i, CTRL, 0xF, 0xF, false));
}
__device__ __forceinline__ float shflx(float v, int m) { return __shfl_xor(v, m, 64); }

__device__ __forceinline__ float wave_sum(float v, int lane) {
  v += dppf<0xB1>(v);
  v += dppf<0x4E>(v);
  v += dppf<0x141>(v);
  v += dppf<0x140>(v);
#if USE_PERMLANE
  { auto r = __builtin_amdgcn_permlane16_swap(__float_as_uint(v), __float_as_uint(v), false, false);
    v = __uint_as_float(r[0]) + __uint_as_float(r[1]); }
  { auto r = __builtin_amdgcn_permlane32_swap(__float_as_uint(v), __float_as_uint(v), false, false);
    v = __uint_as_float(r[0]) + __uint_as_float(r[1]); }
#else
  v += shflx(v, 16);
  v += shflx(v, 32);
#endif
  return v;
}

// ---------------- packed fp16 primitives ----------------
__device__ __forceinline__ u32 pk_mul_h(u32 a, u32 b) {
  u32 d; asm("v_pk_mul_f16 %0, %1, %2" : "=v"(d) : "v"(a), "v"(b)); return d;
}
__device__ __forceinline__ u32 pk_fma_h(u32 a, u32 b, u32 c) {
  u32 d; asm("v_pk_fma_f16 %0, %1, %2, %3" : "=v"(d) : "v"(a), "v"(b), "v"(c)); return d;
}
// src0 read with halves swapped ({im,re}) — free re<->im swap for the i-terms
__device__ __forceinline__ u32 pk_fma_hsw(u32 a, u32 b, u32 c) {
  u32 d;
  asm("v_pk_fma_f16 %0, %1, %2, %3 op_sel:[1,0,0] op_sel_hi:[0,1,1]"
      : "=v"(d) : "v"(a), "v"(b), "v"(c));
  return d;
}

// pack two f32 -> fp16 pair {lo, hi}
__device__ __forceinline__ u32 pk2(float lo, float hi) {
  auto h = __builtin_amdgcn_cvt_pkrtz(lo, hi);
  return __builtin_bit_cast(u32, h);
}

// new = O*a + P*q; s = { {Or,Or}, {-Oi,Oi}, {Pr,Pr}, {-Pi,Pi} } packed fp16
__device__ __forceinline__ u32 updh(u32 a, u32 q, const uint4 s) {
  u32 t = pk_mul_h(a, s.x);
  t = pk_fma_hsw(a, s.y, t);
  t = pk_fma_h(q, s.z, t);
  t = pk_fma_hsw(q, s.w, t);
  return t;
}

template<int L, int W>
__device__ __forceinline__ void gate(u32 a[16], const u32* __restrict__ Ush, int lane) {
  constexpr unsigned PRT = CIRC.g[L][W].prt;
  constexpr unsigned SEL = CIRC.g[L][W].sel;
  constexpr int PLm = (int)(PRT >> 4), PRm = (int)(PRT & 15u);
  constexpr int SLm = (int)(SEL >> 4), SRm = (int)(SEL & 15u);

  int hl = 0;
  if constexpr (SLm != 0) hl = __popc(lane & SLm) & 1;

  // cA: coeffs for slots with class ct=0; cB: ct=1
  const u32* gb = Ush + (L * 10 + W - 10) * 8;
  const uint4 cA = *(const uint4*)(gb + (hl << 2));
  uint4 cB;
  if constexpr (SRm != 0) cB = *(const uint4*)(gb + ((hl ^ 1) << 2));
  else                    cB = cA;

  int bpa = 0;
  if constexpr (use_ds_mask(PLm) && (PLm & 32) != 0) bpa = (lane ^ PLm) << 2;

  if constexpr (PLm == 0) {
    // register-space gate
    constexpr int LB = PRm & (-PRm);
#pragma unroll
    for (int t0 = 0; t0 < 16; ++t0) {
      if (t0 & LB) continue;
      const int t1 = t0 ^ PRm;
      const uint4 s0 = (__builtin_popcount((unsigned)(t0 & SRm)) & 1) ? cB : cA;
      const uint4 s1 = (__builtin_popcount((unsigned)(t1 & SRm)) & 1) ? cB : cA;
      const u32 a0 = a[t0], a1 = a[t1];
      a[t0] = updh(a0, a1, s0);
      a[t1] = updh(a1, a0, s1);
    }
  } else if constexpr (PRm == 0) {
    // lane-crossing, same reg
#pragma unroll
    for (int t = 0; t < 16; ++t) {
      const u32 q = lshuf<PLm>(a[t], lane, bpa);
      const uint4 s = (__builtin_popcount((unsigned)(t & SRm)) & 1) ? cB : cA;
      a[t] = updh(a[t], q, s);
    }
  } else {
    // lane-crossing with reg pairing
    constexpr int LB = PRm & (-PRm);
#pragma unroll
    for (int t0 = 0; t0 < 16; ++t0) {
      if (t0 & LB) continue;
      const int t1 = t0 ^ PRm;
      const u32 q0 = lshuf<PLm>(a[t1], lane, bpa);
      const u32 q1 = lshuf<PLm>(a[t0], lane, bpa);
      const uint4 s0 = (__builtin_popcount((unsigned)(t0 & SRm)) & 1) ? cB : cA;
      const uint4 s1 = (__builtin_popcount((unsigned)(t1 & SRm)) & 1) ? cB : cA;
      a[t0] = updh(a[t0], q0, s0);
      a[t1] = updh(a[t1], q1, s1);
    }
  }
}

template<int L, int W>
__device__ __forceinline__ void layer_from(u32 a[16], const u32* __restrict__ Ush, int lane) {
  if constexpr (W < 10) {
    gate<L, W>(a, Ush, lane);
    layer_from<L, W + 1>(a, Ush, lane);
  }
}

// ---------------- main kernel: one wave per sample ----------------
__global__ __launch_bounds__(256, 4) void qnn_kernel(
    const float* __restrict__ x, const float* __restrict__ Wpre,
    const float* __restrict__ bpre, const float* __restrict__ qw,
    const float* __restrict__ Wpost, const float* __restrict__ bpost,
    float* __restrict__ out)
{
  // gates 10..39: 8 u32 each (2 classes x 4 packed coeff words) at (g-10)*8
  // layer-0 raw f32 coeffs (for embedding fold) at 240 + w*8
  __shared__ __align__(16) u32 Ush[320];

  const int tid = threadIdx.x;
  if (tid < 40) {
    const float phi = qw[tid * 3 + 0];
    const float th  = qw[tid * 3 + 1];
    const float om  = qw[tid * 3 + 2];
    const float c = cosf(0.5f * th), s_ = sinf(0.5f * th);
    const float A  = c;
    const float Br = -cosf(phi) * s_, Bi = -sinf(phi) * s_;
    const float Cr =  cosf(om)  * s_, Ci =  sinf(om)  * s_;
    const float Dr =  cosf(phi + om) * c, Di = sinf(phi + om) * c;
    if (tid < 10) {
      u32* q = &Ush[240 + tid * 8];
      q[0] = __float_as_uint(A);  q[1] = __float_as_uint(Br);
      q[2] = __float_as_uint(Bi); q[3] = __float_as_uint(Cr);
      q[4] = __float_as_uint(Ci); q[5] = __float_as_uint(Dr);
      q[6] = __float_as_uint(Di); q[7] = 0u;
    } else {
      u32* p = &Ush[(tid - 10) * 8];
      // class0 (hi=0): O=(A,0),  P=(Br,Bi)
      p[0] = pk2(A, A);   p[1] = pk2(0.f, 0.f);
      p[2] = pk2(Br, Br); p[3] = pk2(-Bi, Bi);
      // class1 (hi=1): O=(Dr,Di), P=(Cr,Ci)
      p[4] = pk2(Dr, Dr); p[5] = pk2(-Di, Di);
      p[6] = pk2(Cr, Cr); p[7] = pk2(-Ci, Ci);
    }
  }
  __syncthreads();

  const int lane = tid & 63;
  const int b = blockIdx.x * 4 + (tid >> 6);

  // ---- pre-net: angles = tanh(x @ Wpre^T + bpre) (f32) ----
  const float* xrow = x + (size_t)b * 128;
  const float x0 = xrow[lane];
  const float x1 = xrow[lane + 64];
  float cw[10], sw[10];
#pragma unroll
  for (int w = 0; w < 10; ++w) {
    float p = fmaf(x0, Wpre[w * 128 + lane], x1 * Wpre[w * 128 + 64 + lane]);
    p = wave_sum(p, lane);
    const float e = __expf(2.f * (p + bpre[w]));
    const float ang = 1.f - 2.f * __builtin_amdgcn_rcpf(e + 1.f);
    const float h = 0.5f * ang;
    cw[w] = __cosf(h);
    sw[w] = __sinf(h);
  }

  // ---- embedding with layer-0 fold (f32): psi = tensor_w [Rot_w0 . (cos h, -i sin h)] ----
  float u0r[10], u0i[10], u1r[10], u1i[10];
#pragma unroll
  for (int w = 0; w < 10; ++w) {
    const u32* q = &Ush[240 + w * 8];
    const float A = __uint_as_float(q[0]), Br = __uint_as_float(q[1]);
    const float Bi = __uint_as_float(q[2]), Cr = __uint_as_float(q[3]);
    const float Ci = __uint_as_float(q[4]), Dr = __uint_as_float(q[5]);
    const float Di = __uint_as_float(q[6]);
    const float ch = cw[w], sh = sw[w];
    u0r[w] = fmaf(A, ch, Bi * sh);
    u0i[w] = -Br * sh;
    u1r[w] = fmaf(Cr, ch, Di * sh);
    u1i[w] = fmaf(Ci, ch, -Dr * sh);
  }

  // lane factor: wires 0..5 <-> lane bits 5..0
  float Lr, Li;
  {
    const int b0 = (lane >> 5) & 1;
    Lr = b0 ? u1r[0] : u0r[0];
    Li = b0 ? u1i[0] : u0i[0];
  }
#pragma unroll
  for (int w = 1; w < 6; ++w) {
    const int bb = (lane >> (5 - w)) & 1;
    const float arv = bb ? u1r[w] : u0r[w];
    const float aiv = bb ? u1i[w] : u0i[w];
    const float nr = fmaf(Lr, arv, -Li * aiv);
    const float ni = fmaf(Lr, aiv, Li * arv);
    Lr = nr; Li = ni;
  }

  // reg factors: t bits [3:2] = wires 6,7; bits [1:0] = wires 8,9
  float t4r[4], t4i[4], lsr[4], lsi[4];
#pragma unroll
  for (int aa = 0; aa < 2; ++aa) {
#pragma unroll
    for (int c2 = 0; c2 < 2; ++c2) {
      const int k = (aa << 1) | c2;
      const float ar6 = aa ? u1r[6] : u0r[6], ai6 = aa ? u1i[6] : u0i[6];
      const float ar7 = c2 ? u1r[7] : u0r[7], ai7 = c2 ? u1i[7] : u0i[7];
      t4r[k] = fmaf(ar6, ar7, -ai6 * ai7);
      t4i[k] = fmaf(ar6, ai7, ai6 * ar7);
      const float ar8 = aa ? u1r[8] : u0r[8], ai8 = aa ? u1i[8] : u0i[8];
      const float ar9 = c2 ? u1r[9] : u0r[9], ai9 = c2 ? u1i[9] : u0i[9];
      const float s4r = fmaf(ar8, ar9, -ai8 * ai9);
      const float s4i = fmaf(ar8, ai9, ai8 * ar9);
      lsr[k] = fmaf(s4r, Lr, -s4i * Li);
      lsi[k] = fmaf(s4r, Li, s4i * Lr);
    }
  }

  // state: 16 packed fp16 {re,im} amps
  u32 a[16];
#pragma unroll
  for (int t = 0; t < 16; ++t) {
    const int hi4 = t >> 2, lo4 = t & 3;
    const float re = fmaf(t4r[hi4], lsr[lo4], -t4i[hi4] * lsi[lo4]);
    const float im = fmaf(t4r[hi4], lsi[lo4],  t4i[hi4] * lsr[lo4]);
    a[t] = pk2(re, im);
  }

  // ---- layers 1..3 in packed fp16 ----
  layer_from<1, 0>(a, Ush, lane);
  layer_from<2, 0>(a, Ush, lane);
  layer_from<3, 0>(a, Ush, lane);

  // ---- epilogue (f32): acc = sum_p |a|^2 * g(p); g via 16-pt WHT over reg bits ----
  float Wl[10];
#pragma unroll
  for (int i = 0; i < 10; ++i) {
    const int sl = (int)(CIRC.srow[i] >> 4);
    const int par = __popc(lane & sl) & 1;
    const float wv = Wpost[i];
    Wl[i] = par ? -wv : wv;
  }
  float G[16];
#pragma unroll
  for (int m = 0; m < 16; ++m) G[m] = 0.f;
#pragma unroll
  for (int i = 0; i < 10; ++i) G[CIRC.srow[i] & 15u] += Wl[i];
#pragma unroll
  for (int bit = 1; bit < 16; bit <<= 1) {
#pragma unroll
    for (int m = 0; m < 16; ++m) {
      if (!(m & bit)) {
        const float t = G[m];
        G[m] = t + G[m ^ bit];
        G[m ^ bit] = t - G[m ^ bit];
      }
    }
  }

  union H2U { u32 u; _Float16 h[2]; };
  float acc = 0.f;
#pragma unroll
  for (int t = 0; t < 16; ++t) {
    H2U z; z.u = a[t];
    const float rr = (float)z.h[0];
    const float ii = (float)z.h[1];
    acc = fmaf(fmaf(rr, rr, ii * ii), G[t], acc);
  }
  acc = wave_sum(acc, lane);

  if (lane == 0) {
    const float z = acc + bpost[0];
    out[b] = __builtin_amdgcn_rcpf(1.f + __expf(-z));
  }
}

extern "C" void kernel_launch(void* const* d_in, const int* in_sizes, int n_in,
                              void* d_out, int out_size, void* d_ws, size_t ws_size,
                              hipStream_t stream) {
  const float* x     = (const float*)d_in[0];
  const float* Wpre  = (const float*)d_in[1];
  const float* bpre  = (const float*)d_in[2];
  const float* qw    = (const float*)d_in[3];
  const float* Wpost = (const float*)d_in[4];
  const float* bpost = (const float*)d_in[5];
  float* out = (float*)d_out;

  (void)in_sizes; (void)n_in; (void)out_size; (void)d_ws; (void)ws_size;

  qnn_kernel<<<BATCH / 4, 256, 0, stream>>>(x, Wpre, bpre, qw, Wpost, bpost, out);
}

// Round 10
// 167.501 us; speedup vs baseline: 1.1123x; 1.1123x over previous
//
#include <hip/hip_runtime.h>
#include <math.h>

#define BATCH 32768

typedef unsigned int u32;

#if defined(__has_builtin)
#if __has_builtin(__builtin_amdgcn_permlane32_swap) && __has_builtin(__builtin_amdgcn_permlane16_swap)
#define USE_PERMLANE 1
#else
#define USE_PERMLANE 0
#endif
#if __has_builtin(__builtin_amdgcn_fdot2)
#define HAS_FDOT2 1
#else
#define HAS_FDOT2 0
#endif
#else
#define USE_PERMLANE 0
#define HAS_FDOT2 0
#endif

// ---------------------------------------------------------------------------
// Compile-time circuit derivation (lazy CNOT tracking over GF(2)).
// Physical index p (10 bits): lane = p>>4 (bits 9..4), reg t = p&15.
// One amp = one u32 = packed fp16 {re(lo), im(hi)}.
// Layer 0 folded into the embedding; layers 1..3 are generalized pair-mix
// gates with compile-time partner/select masks.
// ---------------------------------------------------------------------------
struct GateC { unsigned prt, sel; };
struct CircuitT { GateC g[4][10]; unsigned srow[10]; };

constexpr CircuitT make_circuit() {
  CircuitT C{};
  unsigned row[10], col[10];
  for (int b = 0; b < 10; ++b) { row[b] = 1u << b; col[b] = 1u << b; }
  for (int l = 0; l < 4; ++l) {
    for (int w = 0; w < 10; ++w) {
      C.g[l][w].prt = col[9 - w];
      C.g[l][w].sel = row[9 - w];
    }
    const int r = (l % 9) + 1;
    for (int w = 0; w < 10; ++w) {
      const int c = w, t = (w + r) % 10;
      const int bc = 9 - c, bt = 9 - t;
      row[bt] ^= row[bc];
      col[bc] ^= col[bt];
    }
  }
  for (int i = 0; i < 10; ++i) C.srow[i] = row[9 - i];
  return C;
}
constexpr CircuitT CIRC = make_circuit();

// Within-layer gate order: gates of one layer act on distinct logical wires
// (CNOTs folded between layers) -> they commute; interleave DS-shuffle gates
// with REG/DPP gates so swizzle latency hides under independent VOP3P work.
constexpr int ORD[4][10] = {
  {0,1,2,3,4,5,6,7,8,9},      // layer 0: folded (unused)
  {0,6,1,7,2,8,3,4,9,5},      // DS,REG,DS,REG,DS,REG,DS,DPP,DS,DPP
  {0,2,1,3,7,4,8,5,9,6},      // DS,DPP,DS,DPP,DS,DPP,DS,DPP,DS,REG
  {0,3,1,2,4,5,6,7,8,9},      // DS,DPP,then 8x DS
};

// ---------------- cross-lane primitives (u32) ----------------
template<int CTRL>
__device__ __forceinline__ u32 dppu(u32 v) {
  return (u32)__builtin_amdgcn_update_dpp((int)v, (int)v, CTRL, 0xF, 0xF, false);
}

template<int LOW>
__device__ __forceinline__ u32 dpp_low(u32 v) {
  static_assert(LOW >= 0 && LOW <= 15, "bad mask");
  if constexpr (LOW == 0) return v;
  else if constexpr (LOW == 1) return dppu<0xB1>(v);        // quad [1,0,3,2]
  else if constexpr (LOW == 2) return dppu<0x4E>(v);        // quad [2,3,0,1]
  else if constexpr (LOW == 3) return dppu<0x1B>(v);        // quad [3,2,1,0]
  else if constexpr (LOW == 7) return dppu<0x141>(v);       // row_half_mirror
  else if constexpr (LOW == 15) return dppu<0x140>(v);      // row_mirror
  else if constexpr (LOW >= 4 && LOW <= 6) return dpp_low<LOW ^ 7>(dppu<0x141>(v));
  else return dpp_low<LOW ^ 15>(dppu<0x140>(v));            // 8..14
}

constexpr int dpp_ops_low(int low) {
  if (low == 0) return 0;
  if (low == 1 || low == 2 || low == 3 || low == 7 || low == 15) return 1;
  if ((low >= 4 && low <= 6) || low == 8 || (low >= 12 && low <= 14)) return 2;
  return 3;
}
constexpr int chain_cost(int M) {
#if !USE_PERMLANE
  if (M & 48) return 99;
#endif
  return ((M & 32) ? 2 : 0) + ((M & 16) ? 2 : 0) + dpp_ops_low(M & 15);
}
// Round-9 A/B showed VALU is the binding pipe (DS->VALU flip cost +9%):
// keep only single-DPP masks on VALU (round-8 config, best measured).
constexpr bool use_ds_mask(int M) { return chain_cost(M) >= 2; }

#if USE_PERMLANE
__device__ __forceinline__ u32 xor16u(u32 v, int lane) {
  auto r = __builtin_amdgcn_permlane16_swap(v, v, false, false);
  return (lane & 16) ? r[0] : r[1];
}
__device__ __forceinline__ u32 xor32u(u32 v, int lane) {
  auto r = __builtin_amdgcn_permlane32_swap(v, v, false, false);
  return (lane & 32) ? r[0] : r[1];
}
#else
__device__ __forceinline__ u32 xor16u(u32 v, int lane) { return (u32)__shfl_xor((int)v, 16, 64); }
__device__ __forceinline__ u32 xor32u(u32 v, int lane) { return (u32)__shfl_xor((int)v, 32, 64); }
#endif

template<int M>
__device__ __forceinline__ u32 lshuf(u32 v, int lane, int bpa) {
  if constexpr (use_ds_mask(M)) {
    if constexpr ((M & 32) != 0) {
      return (u32)__builtin_amdgcn_ds_bpermute(bpa, (int)v);
    } else {
      return (u32)__builtin_amdgcn_ds_swizzle((int)v, 0x1F | (M << 10));
    }
  } else {
    u32 t = v;
    if constexpr ((M & 32) != 0) t = xor32u(t, lane);
    if constexpr ((M & 16) != 0) t = xor16u(t, lane);
    if constexpr ((M & 15) != 0) t = dpp_low<M & 15>(t);
    return t;
  }
}

// ---------------- float cross-lane (prenet/epilogue) ----------------
template<int CTRL>
__device__ __forceinline__ float dppf(float v) {
  const int i = __float_as_int(v);
  return __int_as_float(__builtin_amdgcn_update_dpp(i, i, CTRL, 0xF, 0xF, false));
}
__device__ __forceinline__ float shflx(float v, int m) { return __shfl_xor(v, m, 64); }

__device__ __forceinline__ float wave_sum(float v, int lane) {
  v += dppf<0xB1>(v);
  v += dppf<0x4E>(v);
  v += dppf<0x141>(v);
  v += dppf<0x140>(v);
#if USE_PERMLANE
  { auto r = __builtin_amdgcn_permlane16_swap(__float_as_uint(v), __float_as_uint(v), false, false);
    v = __uint_as_float(r[0]) + __uint_as_float(r[1]); }
  { auto r = __builtin_amdgcn_permlane32_swap(__float_as_uint(v), __float_as_uint(v), false, false);
    v = __uint_as_float(r[0]) + __uint_as_float(r[1]); }
#else
  v += shflx(v, 16);
  v += shflx(v, 32);
#endif
  return v;
}

// ---------------- packed fp16 primitives ----------------
__device__ __forceinline__ u32 pk_mul_h(u32 a, u32 b) {
  u32 d; asm("v_pk_mul_f16 %0, %1, %2" : "=v"(d) : "v"(a), "v"(b)); return d;
}
__device__ __forceinline__ u32 pk_fma_h(u32 a, u32 b, u32 c) {
  u32 d; asm("v_pk_fma_f16 %0, %1, %2, %3" : "=v"(d) : "v"(a), "v"(b), "v"(c)); return d;
}
// src0 read with halves swapped ({im,re}) — free re<->im swap for the i-terms
__device__ __forceinline__ u32 pk_fma_hsw(u32 a, u32 b, u32 c) {
  u32 d;
  asm("v_pk_fma_f16 %0, %1, %2, %3 op_sel:[1,0,0] op_sel_hi:[0,1,1]"
      : "=v"(d) : "v"(a), "v"(b), "v"(c));
  return d;
}

// pack two f32 -> fp16 pair {lo, hi}
__device__ __forceinline__ u32 pk2(float lo, float hi) {
  auto h = __builtin_amdgcn_cvt_pkrtz(lo, hi);
  return __builtin_bit_cast(u32, h);
}

// new = O*a + P*q; s = { {Or,Or}, {-Oi,Oi}, {Pr,Pr}, {-Pi,Pi} } packed fp16
__device__ __forceinline__ u32 updh(u32 a, u32 q, const uint4 s) {
  u32 t = pk_mul_h(a, s.x);
  t = pk_fma_hsw(a, s.y, t);
  t = pk_fma_h(q, s.z, t);
  t = pk_fma_hsw(q, s.w, t);
  return t;
}

template<int L, int W>
__device__ __forceinline__ void gate(u32 a[16], const u32* __restrict__ Ush, int lane) {
  constexpr unsigned PRT = CIRC.g[L][W].prt;
  constexpr unsigned SEL = CIRC.g[L][W].sel;
  constexpr int PLm = (int)(PRT >> 4), PRm = (int)(PRT & 15u);
  constexpr int SLm = (int)(SEL >> 4), SRm = (int)(SEL & 15u);

  int hl = 0;
  if constexpr (SLm != 0) hl = __popc(lane & SLm) & 1;

  // cA: coeffs for slots with class ct=0; cB: ct=1
  const u32* gb = Ush + (L * 10 + W - 10) * 8;
  const uint4 cA = *(const uint4*)(gb + (hl << 2));
  uint4 cB;
  if constexpr (SRm != 0) cB = *(const uint4*)(gb + ((hl ^ 1) << 2));
  else                    cB = cA;

  int bpa = 0;
  if constexpr (use_ds_mask(PLm) && (PLm & 32) != 0) bpa = (lane ^ PLm) << 2;

  if constexpr (PLm == 0) {
    // register-space gate
    constexpr int LB = PRm & (-PRm);
#pragma unroll
    for (int t0 = 0; t0 < 16; ++t0) {
      if (t0 & LB) continue;
      const int t1 = t0 ^ PRm;
      const uint4 s0 = (__builtin_popcount((unsigned)(t0 & SRm)) & 1) ? cB : cA;
      const uint4 s1 = (__builtin_popcount((unsigned)(t1 & SRm)) & 1) ? cB : cA;
      const u32 a0 = a[t0], a1 = a[t1];
      a[t0] = updh(a0, a1, s0);
      a[t1] = updh(a1, a0, s1);
    }
  } else if constexpr (PRm == 0) {
    // lane-crossing, same reg
#pragma unroll
    for (int t = 0; t < 16; ++t) {
      const u32 q = lshuf<PLm>(a[t], lane, bpa);
      const uint4 s = (__builtin_popcount((unsigned)(t & SRm)) & 1) ? cB : cA;
      a[t] = updh(a[t], q, s);
    }
  } else {
    // lane-crossing with reg pairing
    constexpr int LB = PRm & (-PRm);
#pragma unroll
    for (int t0 = 0; t0 < 16; ++t0) {
      if (t0 & LB) continue;
      const int t1 = t0 ^ PRm;
      const u32 q0 = lshuf<PLm>(a[t1], lane, bpa);
      const u32 q1 = lshuf<PLm>(a[t0], lane, bpa);
      const uint4 s0 = (__builtin_popcount((unsigned)(t0 & SRm)) & 1) ? cB : cA;
      const uint4 s1 = (__builtin_popcount((unsigned)(t1 & SRm)) & 1) ? cB : cA;
      a[t0] = updh(a[t0], q0, s0);
      a[t1] = updh(a[t1], q1, s1);
    }
  }
}

template<int L, int K>
__device__ __forceinline__ void layer_from(u32 a[16], const u32* __restrict__ Ush, int lane) {
  if constexpr (K < 10) {
    gate<L, ORD[L][K]>(a, Ush, lane);
    layer_from<L, K + 1>(a, Ush, lane);
  }
}

// ---------------- main kernel: one wave per sample ----------------
__global__ __launch_bounds__(256, 4) void qnn_kernel(
    const float* __restrict__ x, const float* __restrict__ Wpre,
    const float* __restrict__ bpre, const float* __restrict__ qw,
    const float* __restrict__ Wpost, const float* __restrict__ bpost,
    float* __restrict__ out)
{
  // gates 10..39: 8 u32 each (2 classes x 4 packed coeff words) at (g-10)*8
  // layer-0 raw f32 coeffs (for embedding fold) at 240 + w*8
  __shared__ __align__(16) u32 Ush[320];
  // g-table: g(lane,t) = sum_i +-Wpost[i]; identical for all waves/blocks.
  // Layout [t][lane] so epilogue reads are lane-stride-1 (conflict-free).
  __shared__ float gtab[16 * 64];

  const int tid = threadIdx.x;
  if (tid < 40) {
    const float phi = qw[tid * 3 + 0];
    const float th  = qw[tid * 3 + 1];
    const float om  = qw[tid * 3 + 2];
    const float c = cosf(0.5f * th), s_ = sinf(0.5f * th);
    const float A  = c;
    const float Br = -cosf(phi) * s_, Bi = -sinf(phi) * s_;
    const float Cr =  cosf(om)  * s_, Ci =  sinf(om)  * s_;
    const float Dr =  cosf(phi + om) * c, Di = sinf(phi + om) * c;
    if (tid < 10) {
      u32* q = &Ush[240 + tid * 8];
      q[0] = __float_as_uint(A);  q[1] = __float_as_uint(Br);
      q[2] = __float_as_uint(Bi); q[3] = __float_as_uint(Cr);
      q[4] = __float_as_uint(Ci); q[5] = __float_as_uint(Dr);
      q[6] = __float_as_uint(Di); q[7] = 0u;
    } else {
      u32* p = &Ush[(tid - 10) * 8];
      // class0 (hi=0): O=(A,0),  P=(Br,Bi)
      p[0] = pk2(A, A);   p[1] = pk2(0.f, 0.f);
      p[2] = pk2(Br, Br); p[3] = pk2(-Bi, Bi);
      // class1 (hi=1): O=(Dr,Di), P=(Cr,Ci)
      p[4] = pk2(Dr, Dr); p[5] = pk2(-Di, Di);
      p[6] = pk2(Cr, Cr); p[7] = pk2(-Ci, Ci);
    }
  }
  // g-table build: 1024 entries / 256 threads = 4 each (once per block)
#pragma unroll
  for (int k = 0; k < 4; ++k) {
    const int idx = tid * 4 + k;
    const int t = idx >> 6;
    const int l6 = idx & 63;
    float g = 0.f;
#pragma unroll
    for (int i = 0; i < 10; ++i) {
      const int sl = (int)(CIRC.srow[i] >> 4);
      const int sr = (int)(CIRC.srow[i] & 15u);
      const int par = (__popc(l6 & sl) + __popc(t & sr)) & 1;
      const float wv = Wpost[i];
      g += par ? -wv : wv;
    }
    gtab[t * 64 + l6] = g;
  }
  __syncthreads();

  const int lane = tid & 63;
  const int b = blockIdx.x * 4 + (tid >> 6);

  // ---- pre-net: angles = tanh(x @ Wpre^T + bpre) (f32) ----
  const float* xrow = x + (size_t)b * 128;
  const float x0 = xrow[lane];
  const float x1 = xrow[lane + 64];
  float cw[10], sw[10];
#pragma unroll
  for (int w = 0; w < 10; ++w) {
    float p = fmaf(x0, Wpre[w * 128 + lane], x1 * Wpre[w * 128 + 64 + lane]);
    p = wave_sum(p, lane);
    const float e = __expf(2.f * (p + bpre[w]));
    const float ang = 1.f - 2.f * __builtin_amdgcn_rcpf(e + 1.f);
    const float h = 0.5f * ang;
    cw[w] = __cosf(h);
    sw[w] = __sinf(h);
  }

  // ---- embedding with layer-0 fold (f32): psi = tensor_w [Rot_w0 . (cos h, -i sin h)] ----
  float u0r[10], u0i[10], u1r[10], u1i[10];
#pragma unroll
  for (int w = 0; w < 10; ++w) {
    const u32* q = &Ush[240 + w * 8];
    const float A = __uint_as_float(q[0]), Br = __uint_as_float(q[1]);
    const float Bi = __uint_as_float(q[2]), Cr = __uint_as_float(q[3]);
    const float Ci = __uint_as_float(q[4]), Dr = __uint_as_float(q[5]);
    const float Di = __uint_as_float(q[6]);
    const float ch = cw[w], sh = sw[w];
    u0r[w] = fmaf(A, ch, Bi * sh);
    u0i[w] = -Br * sh;
    u1r[w] = fmaf(Cr, ch, Di * sh);
    u1i[w] = fmaf(Ci, ch, -Dr * sh);
  }

  // lane factor: wires 0..5 <-> lane bits 5..0
  float Lr, Li;
  {
    const int b0 = (lane >> 5) & 1;
    Lr = b0 ? u1r[0] : u0r[0];
    Li = b0 ? u1i[0] : u0i[0];
  }
#pragma unroll
  for (int w = 1; w < 6; ++w) {
    const int bb = (lane >> (5 - w)) & 1;
    const float arv = bb ? u1r[w] : u0r[w];
    const float aiv = bb ? u1i[w] : u0i[w];
    const float nr = fmaf(Lr, arv, -Li * aiv);
    const float ni = fmaf(Lr, aiv, Li * arv);
    Lr = nr; Li = ni;
  }

  // reg factors: t bits [3:2] = wires 6,7; bits [1:0] = wires 8,9
  float t4r[4], t4i[4], lsr[4], lsi[4];
#pragma unroll
  for (int aa = 0; aa < 2; ++aa) {
#pragma unroll
    for (int c2 = 0; c2 < 2; ++c2) {
      const int k = (aa << 1) | c2;
      const float ar6 = aa ? u1r[6] : u0r[6], ai6 = aa ? u1i[6] : u0i[6];
      const float ar7 = c2 ? u1r[7] : u0r[7], ai7 = c2 ? u1i[7] : u0i[7];
      t4r[k] = fmaf(ar6, ar7, -ai6 * ai7);
      t4i[k] = fmaf(ar6, ai7, ai6 * ar7);
      const float ar8 = aa ? u1r[8] : u0r[8], ai8 = aa ? u1i[8] : u0i[8];
      const float ar9 = c2 ? u1r[9] : u0r[9], ai9 = c2 ? u1i[9] : u0i[9];
      const float s4r = fmaf(ar8, ar9, -ai8 * ai9);
      const float s4i = fmaf(ar8, ai9, ai8 * ar9);
      lsr[k] = fmaf(s4r, Lr, -s4i * Li);
      lsi[k] = fmaf(s4r, Li, s4i * Lr);
    }
  }

  // state: 16 packed fp16 {re,im} amps
  u32 a[16];
#pragma unroll
  for (int t = 0; t < 16; ++t) {
    const int hi4 = t >> 2, lo4 = t & 3;
    const float re = fmaf(t4r[hi4], lsr[lo4], -t4i[hi4] * lsi[lo4]);
    const float im = fmaf(t4r[hi4], lsi[lo4],  t4i[hi4] * lsr[lo4]);
    a[t] = pk2(re, im);
  }

  // ---- layers 1..3 in packed fp16 (interleaved commuting order) ----
  layer_from<1, 0>(a, Ush, lane);
  layer_from<2, 0>(a, Ush, lane);
  layer_from<3, 0>(a, Ush, lane);

  // ---- epilogue: acc = sum_t |a|^2 * gtab[t][lane]; reduce across lanes ----
  float acc = 0.f;
#pragma unroll
  for (int t = 0; t < 16; ++t) {
    const float g = gtab[t * 64 + lane];
    float p;
#if HAS_FDOT2
    typedef _Float16 h2 __attribute__((ext_vector_type(2)));
    const h2 ah = __builtin_bit_cast(h2, a[t]);
    p = __builtin_amdgcn_fdot2(ah, ah, 0.f, false);
#else
    union H2U { u32 u; _Float16 h[2]; } z;
    z.u = a[t];
    const float rr = (float)z.h[0];
    const float ii = (float)z.h[1];
    p = fmaf(rr, rr, ii * ii);
#endif
    acc = fmaf(p, g, acc);
  }
  acc = wave_sum(acc, lane);

  if (lane == 0) {
    const float z = acc + bpost[0];
    out[b] = __builtin_amdgcn_rcpf(1.f + __expf(-z));
  }
}

extern "C" void kernel_launch(void* const* d_in, const int* in_sizes, int n_in,
                              void* d_out, int out_size, void* d_ws, size_t ws_size,
                              hipStream_t stream) {
  const float* x     = (const float*)d_in[0];
  const float* Wpre  = (const float*)d_in[1];
  const float* bpre  = (const float*)d_in[2];
  const float* qw    = (const float*)d_in[3];
  const float* Wpost = (const float*)d_in[4];
  const float* bpost = (const float*)d_in[5];
  float* out = (float*)d_out;

  (void)in_sizes; (void)n_in; (void)out_size; (void)d_ws; (void)ws_size;

  qnn_kernel<<<BATCH / 4, 256, 0, stream>>>(x, Wpre, bpre, qw, Wpost, bpost, out);
}

// Round 11
// 167.017 us; speedup vs baseline: 1.1155x; 1.0029x over previous
//
#include <hip/hip_runtime.h>
#include <math.h>

#define BATCH 32768

typedef unsigned int u32;

#if defined(__has_builtin)
#if __has_builtin(__builtin_amdgcn_permlane32_swap) && __has_builtin(__builtin_amdgcn_permlane16_swap)
#define USE_PERMLANE 1
#else
#define USE_PERMLANE 0
#endif
#if __has_builtin(__builtin_amdgcn_fdot2)
#define HAS_FDOT2 1
#else
#define HAS_FDOT2 0
#endif
#else
#define USE_PERMLANE 0
#define HAS_FDOT2 0
#endif

// ---------------------------------------------------------------------------
// Compile-time circuit derivation (lazy CNOT tracking over GF(2)).
// Physical index p (10 bits): lane = p>>4 (bits 9..4), reg t = p&15.
// One amp = one u32 = packed fp16 {re(lo), im(hi)}.
// Layer 0 folded into the embedding; layers 1..3 are generalized pair-mix
// gates with compile-time partner/select masks.
// ---------------------------------------------------------------------------
struct GateC { unsigned prt, sel; };
struct CircuitT { GateC g[4][10]; unsigned srow[10]; };

constexpr CircuitT make_circuit() {
  CircuitT C{};
  unsigned row[10], col[10];
  for (int b = 0; b < 10; ++b) { row[b] = 1u << b; col[b] = 1u << b; }
  for (int l = 0; l < 4; ++l) {
    for (int w = 0; w < 10; ++w) {
      C.g[l][w].prt = col[9 - w];
      C.g[l][w].sel = row[9 - w];
    }
    const int r = (l % 9) + 1;
    for (int w = 0; w < 10; ++w) {
      const int c = w, t = (w + r) % 10;
      const int bc = 9 - c, bt = 9 - t;
      row[bt] ^= row[bc];
      col[bc] ^= col[bt];
    }
  }
  for (int i = 0; i < 10; ++i) C.srow[i] = row[9 - i];
  return C;
}
constexpr CircuitT CIRC = make_circuit();

// Within-layer gate order (commuting gates; interleave DS-heavy with REG/DPP).
constexpr int ORD[4][10] = {
  {0,1,2,3,4,5,6,7,8,9},      // layer 0: folded (unused)
  {0,6,1,7,2,8,3,4,9,5},
  {0,2,1,3,7,4,8,5,9,6},
  {0,3,1,2,4,5,6,7,8,9},
};

// ---------------- cross-lane primitives (u32) ----------------
template<int CTRL>
__device__ __forceinline__ u32 dppu(u32 v) {
  return (u32)__builtin_amdgcn_update_dpp((int)v, (int)v, CTRL, 0xF, 0xF, false);
}

template<int LOW>
__device__ __forceinline__ u32 dpp_low(u32 v) {
  static_assert(LOW >= 0 && LOW <= 15, "bad mask");
  if constexpr (LOW == 0) return v;
  else if constexpr (LOW == 1) return dppu<0xB1>(v);        // quad [1,0,3,2]
  else if constexpr (LOW == 2) return dppu<0x4E>(v);        // quad [2,3,0,1]
  else if constexpr (LOW == 3) return dppu<0x1B>(v);        // quad [3,2,1,0]
  else if constexpr (LOW == 7) return dppu<0x141>(v);       // row_half_mirror
  else if constexpr (LOW == 15) return dppu<0x140>(v);      // row_mirror
  else if constexpr (LOW >= 4 && LOW <= 6) return dpp_low<LOW ^ 7>(dppu<0x141>(v));
  else return dpp_low<LOW ^ 15>(dppu<0x140>(v));            // 8..14
}

constexpr int dpp_ops_low(int low) {
  if (low == 0) return 0;
  if (low == 1 || low == 2 || low == 3 || low == 7 || low == 15) return 1;
  if ((low >= 4 && low <= 6) || low == 8 || (low >= 12 && low <= 14)) return 2;
  return 3;
}
constexpr int chain_cost(int M) {
#if !USE_PERMLANE
  if (M & 48) return 99;
#endif
  return ((M & 32) ? 2 : 0) + ((M & 16) ? 2 : 0) + dpp_ops_low(M & 15);
}
// Round-9 A/B: DS->VALU-chain flips hurt; keep only single-DPP masks on VALU.
constexpr bool use_ds_mask(int M) { return chain_cost(M) >= 2; }

#if USE_PERMLANE
__device__ __forceinline__ u32 xor16u(u32 v, int lane) {
  auto r = __builtin_amdgcn_permlane16_swap(v, v, false, false);
  return (lane & 16) ? r[0] : r[1];
}
__device__ __forceinline__ u32 xor32u(u32 v, int lane) {
  auto r = __builtin_amdgcn_permlane32_swap(v, v, false, false);
  return (lane & 32) ? r[0] : r[1];
}
#else
__device__ __forceinline__ u32 xor16u(u32 v, int lane) { return (u32)__shfl_xor((int)v, 16, 64); }
__device__ __forceinline__ u32 xor32u(u32 v, int lane) { return (u32)__shfl_xor((int)v, 32, 64); }
#endif

template<int M>
__device__ __forceinline__ u32 lshuf(u32 v, int lane, int bpa) {
  if constexpr (use_ds_mask(M)) {
    if constexpr ((M & 32) != 0) {
      return (u32)__builtin_amdgcn_ds_bpermute(bpa, (int)v);
    } else {
      return (u32)__builtin_amdgcn_ds_swizzle((int)v, 0x1F | (M << 10));
    }
  } else {
    u32 t = v;
    if constexpr ((M & 32) != 0) t = xor32u(t, lane);
    if constexpr ((M & 16) != 0) t = xor16u(t, lane);
    if constexpr ((M & 15) != 0) t = dpp_low<M & 15>(t);
    return t;
  }
}

// ---------------- float cross-lane (prenet/epilogue) ----------------
template<int CTRL>
__device__ __forceinline__ float dppf(float v) {
  const int i = __float_as_int(v);
  return __int_as_float(__builtin_amdgcn_update_dpp(i, i, CTRL, 0xF, 0xF, false));
}
__device__ __forceinline__ float shflx(float v, int m) { return __shfl_xor(v, m, 64); }

__device__ __forceinline__ float wave_sum(float v, int lane) {
  v += dppf<0xB1>(v);
  v += dppf<0x4E>(v);
  v += dppf<0x141>(v);
  v += dppf<0x140>(v);
#if USE_PERMLANE
  { auto r = __builtin_amdgcn_permlane16_swap(__float_as_uint(v), __float_as_uint(v), false, false);
    v = __uint_as_float(r[0]) + __uint_as_float(r[1]); }
  { auto r = __builtin_amdgcn_permlane32_swap(__float_as_uint(v), __float_as_uint(v), false, false);
    v = __uint_as_float(r[0]) + __uint_as_float(r[1]); }
#else
  v += shflx(v, 16);
  v += shflx(v, 32);
#endif
  return v;
}

// ---------------- packed fp16 primitives ----------------
__device__ __forceinline__ u32 pk_mul_h(u32 a, u32 b) {
  u32 d; asm("v_pk_mul_f16 %0, %1, %2" : "=v"(d) : "v"(a), "v"(b)); return d;
}
__device__ __forceinline__ u32 pk_fma_h(u32 a, u32 b, u32 c) {
  u32 d; asm("v_pk_fma_f16 %0, %1, %2, %3" : "=v"(d) : "v"(a), "v"(b), "v"(c)); return d;
}
// src0 read with halves swapped ({im,re}) — free re<->im swap for the i-terms
__device__ __forceinline__ u32 pk_fma_hsw(u32 a, u32 b, u32 c) {
  u32 d;
  asm("v_pk_fma_f16 %0, %1, %2, %3 op_sel:[1,0,0] op_sel_hi:[0,1,1]"
      : "=v"(d) : "v"(a), "v"(b), "v"(c));
  return d;
}

// pack two f32 -> fp16 pair {lo, hi}
__device__ __forceinline__ u32 pk2(float lo, float hi) {
  auto h = __builtin_amdgcn_cvt_pkrtz(lo, hi);
  return __builtin_bit_cast(u32, h);
}

// new = O*a + P*q; s = { {Or,Or}, {-Oi,Oi}, {Pr,Pr}, {-Pi,Pi} } packed fp16
__device__ __forceinline__ u32 updh(u32 a, u32 q, const uint4 s) {
  u32 t = pk_mul_h(a, s.x);
  t = pk_fma_hsw(a, s.y, t);
  t = pk_fma_h(q, s.z, t);
  t = pk_fma_hsw(q, s.w, t);
  return t;
}

template<int L, int W>
__device__ __forceinline__ void gate(u32 a[16], const u32* __restrict__ Ush, int lane) {
  constexpr unsigned PRT = CIRC.g[L][W].prt;
  constexpr unsigned SEL = CIRC.g[L][W].sel;
  constexpr int PLm = (int)(PRT >> 4), PRm = (int)(PRT & 15u);
  constexpr int SLm = (int)(SEL >> 4), SRm = (int)(SEL & 15u);

  int hl = 0;
  if constexpr (SLm != 0) hl = __popc(lane & SLm) & 1;

  // cA: coeffs for slots with class ct=0; cB: ct=1
  const u32* gb = Ush + (L * 10 + W - 10) * 8;
  const uint4 cA = *(const uint4*)(gb + (hl << 2));
  uint4 cB;
  if constexpr (SRm != 0) cB = *(const uint4*)(gb + ((hl ^ 1) << 2));
  else                    cB = cA;

  int bpa = 0;
  if constexpr (use_ds_mask(PLm) && (PLm & 32) != 0) bpa = (lane ^ PLm) << 2;

  if constexpr (PLm == 0) {
    // register-space gate (pairwise swap, no shuffles)
    constexpr int LB = PRm & (-PRm);
#pragma unroll
    for (int t0 = 0; t0 < 16; ++t0) {
      if (t0 & LB) continue;
      const int t1 = t0 ^ PRm;
      const uint4 s0 = (__builtin_popcount((unsigned)(t0 & SRm)) & 1) ? cB : cA;
      const uint4 s1 = (__builtin_popcount((unsigned)(t1 & SRm)) & 1) ? cB : cA;
      const u32 a0 = a[t0], a1 = a[t1];
      a[t0] = updh(a0, a1, s0);
      a[t1] = updh(a1, a0, s1);
    }
  } else {
    // lane-crossing: BATCH all 16 partner shuffles first so their latencies
    // overlap (one wait), then do all 128 VOP3P. Bitwise-identical math.
    u32 q[16];
#pragma unroll
    for (int t = 0; t < 16; ++t)
      q[t] = lshuf<PLm>(a[t ^ PRm], lane, bpa);
#pragma unroll
    for (int t = 0; t < 16; ++t) {
      const uint4 s = (__builtin_popcount((unsigned)(t & SRm)) & 1) ? cB : cA;
      a[t] = updh(a[t], q[t], s);
    }
  }
}

template<int L, int K>
__device__ __forceinline__ void layer_from(u32 a[16], const u32* __restrict__ Ush, int lane) {
  if constexpr (K < 10) {
    gate<L, ORD[L][K]>(a, Ush, lane);
    layer_from<L, K + 1>(a, Ush, lane);
  }
}

// ---------------- main kernel: one wave per sample ----------------
__global__ __launch_bounds__(256, 4) void qnn_kernel(
    const float* __restrict__ x, const float* __restrict__ Wpre,
    const float* __restrict__ bpre, const float* __restrict__ qw,
    const float* __restrict__ Wpost, const float* __restrict__ bpost,
    float* __restrict__ out)
{
  // gates 10..39: 8 u32 each (2 classes x 4 packed coeff words) at (g-10)*8
  // layer-0 raw f32 coeffs (for embedding fold) at 240 + w*8
  __shared__ __align__(16) u32 Ush[320];
  // g-table: g(lane,t) = sum_i +-Wpost[i]; identical for all waves/blocks.
  __shared__ float gtab[16 * 64];

  const int tid = threadIdx.x;
  if (tid < 40) {
    const float phi = qw[tid * 3 + 0];
    const float th  = qw[tid * 3 + 1];
    const float om  = qw[tid * 3 + 2];
    const float c = cosf(0.5f * th), s_ = sinf(0.5f * th);
    const float A  = c;
    const float Br = -cosf(phi) * s_, Bi = -sinf(phi) * s_;
    const float Cr =  cosf(om)  * s_, Ci =  sinf(om)  * s_;
    const float Dr =  cosf(phi + om) * c, Di = sinf(phi + om) * c;
    if (tid < 10) {
      u32* q = &Ush[240 + tid * 8];
      q[0] = __float_as_uint(A);  q[1] = __float_as_uint(Br);
      q[2] = __float_as_uint(Bi); q[3] = __float_as_uint(Cr);
      q[4] = __float_as_uint(Ci); q[5] = __float_as_uint(Dr);
      q[6] = __float_as_uint(Di); q[7] = 0u;
    } else {
      u32* p = &Ush[(tid - 10) * 8];
      // class0 (hi=0): O=(A,0),  P=(Br,Bi)
      p[0] = pk2(A, A);   p[1] = pk2(0.f, 0.f);
      p[2] = pk2(Br, Br); p[3] = pk2(-Bi, Bi);
      // class1 (hi=1): O=(Dr,Di), P=(Cr,Ci)
      p[4] = pk2(Dr, Dr); p[5] = pk2(-Di, Di);
      p[6] = pk2(Cr, Cr); p[7] = pk2(-Ci, Ci);
    }
  }
  // g-table build: 1024 entries / 256 threads = 4 each (once per block)
#pragma unroll
  for (int k = 0; k < 4; ++k) {
    const int idx = tid * 4 + k;
    const int t = idx >> 6;
    const int l6 = idx & 63;
    float g = 0.f;
#pragma unroll
    for (int i = 0; i < 10; ++i) {
      const int sl = (int)(CIRC.srow[i] >> 4);
      const int sr = (int)(CIRC.srow[i] & 15u);
      const int par = (__popc(l6 & sl) + __popc(t & sr)) & 1;
      const float wv = Wpost[i];
      g += par ? -wv : wv;
    }
    gtab[t * 64 + l6] = g;
  }
  __syncthreads();

  const int lane = tid & 63;
  const int b = blockIdx.x * 4 + (tid >> 6);

  // ---- pre-net: angles = tanh(x @ Wpre^T + bpre) (f32) ----
  const float* xrow = x + (size_t)b * 128;
  const float x0 = xrow[lane];
  const float x1 = xrow[lane + 64];
  float cw[10], sw[10];
#pragma unroll
  for (int w = 0; w < 10; ++w) {
    float p = fmaf(x0, Wpre[w * 128 + lane], x1 * Wpre[w * 128 + 64 + lane]);
    p = wave_sum(p, lane);
    const float e = __expf(2.f * (p + bpre[w]));
    const float ang = 1.f - 2.f * __builtin_amdgcn_rcpf(e + 1.f);
    const float h = 0.5f * ang;
    cw[w] = __cosf(h);
    sw[w] = __sinf(h);
  }

  // ---- embedding with layer-0 fold (f32): psi = tensor_w [Rot_w0 . (cos h, -i sin h)] ----
  float u0r[10], u0i[10], u1r[10], u1i[10];
#pragma unroll
  for (int w = 0; w < 10; ++w) {
    const u32* q = &Ush[240 + w * 8];
    const float A = __uint_as_float(q[0]), Br = __uint_as_float(q[1]);
    const float Bi = __uint_as_float(q[2]), Cr = __uint_as_float(q[3]);
    const float Ci = __uint_as_float(q[4]), Dr = __uint_as_float(q[5]);
    const float Di = __uint_as_float(q[6]);
    const float ch = cw[w], sh = sw[w];
    u0r[w] = fmaf(A, ch, Bi * sh);
    u0i[w] = -Br * sh;
    u1r[w] = fmaf(Cr, ch, Di * sh);
    u1i[w] = fmaf(Ci, ch, -Dr * sh);
  }

  // lane factor: wires 0..5 <-> lane bits 5..0
  float Lr, Li;
  {
    const int b0 = (lane >> 5) & 1;
    Lr = b0 ? u1r[0] : u0r[0];
    Li = b0 ? u1i[0] : u0i[0];
  }
#pragma unroll
  for (int w = 1; w < 6; ++w) {
    const int bb = (lane >> (5 - w)) & 1;
    const float arv = bb ? u1r[w] : u0r[w];
    const float aiv = bb ? u1i[w] : u0i[w];
    const float nr = fmaf(Lr, arv, -Li * aiv);
    const float ni = fmaf(Lr, aiv, Li * arv);
    Lr = nr; Li = ni;
  }

  // reg factors: t bits [3:2] = wires 6,7; bits [1:0] = wires 8,9
  float t4r[4], t4i[4], lsr[4], lsi[4];
#pragma unroll
  for (int aa = 0; aa < 2; ++aa) {
#pragma unroll
    for (int c2 = 0; c2 < 2; ++c2) {
      const int k = (aa << 1) | c2;
      const float ar6 = aa ? u1r[6] : u0r[6], ai6 = aa ? u1i[6] : u0i[6];
      const float ar7 = c2 ? u1r[7] : u0r[7], ai7 = c2 ? u1i[7] : u0i[7];
      t4r[k] = fmaf(ar6, ar7, -ai6 * ai7);
      t4i[k] = fmaf(ar6, ai7, ai6 * ar7);
      const float ar8 = aa ? u1r[8] : u0r[8], ai8 = aa ? u1i[8] : u0i[8];
      const float ar9 = c2 ? u1r[9] : u0r[9], ai9 = c2 ? u1i[9] : u0i[9];
      const float s4r = fmaf(ar8, ar9, -ai8 * ai9);
      const float s4i = fmaf(ar8, ai9, ai8 * ar9);
      lsr[k] = fmaf(s4r, Lr, -s4i * Li);
      lsi[k] = fmaf(s4r, Li, s4i * Lr);
    }
  }

  // state: 16 packed fp16 {re,im} amps
  u32 a[16];
#pragma unroll
  for (int t = 0; t < 16; ++t) {
    const int hi4 = t >> 2, lo4 = t & 3;
    const float re = fmaf(t4r[hi4], lsr[lo4], -t4i[hi4] * lsi[lo4]);
    const float im = fmaf(t4r[hi4], lsi[lo4],  t4i[hi4] * lsr[lo4]);
    a[t] = pk2(re, im);
  }

  // ---- layers 1..3 in packed fp16 (batched shuffles per gate) ----
  layer_from<1, 0>(a, Ush, lane);
  layer_from<2, 0>(a, Ush, lane);
  layer_from<3, 0>(a, Ush, lane);

  // ---- epilogue: acc = sum_t |a|^2 * gtab[t][lane]; reduce across lanes ----
  float acc = 0.f;
#pragma unroll
  for (int t = 0; t < 16; ++t) {
    const float g = gtab[t * 64 + lane];
    float p;
#if HAS_FDOT2
    typedef _Float16 h2 __attribute__((ext_vector_type(2)));
    const h2 ah = __builtin_bit_cast(h2, a[t]);
    p = __builtin_amdgcn_fdot2(ah, ah, 0.f, false);
#else
    union H2U { u32 u; _Float16 h[2]; } z;
    z.u = a[t];
    const float rr = (float)z.h[0];
    const float ii = (float)z.h[1];
    p = fmaf(rr, rr, ii * ii);
#endif
    acc = fmaf(p, g, acc);
  }
  acc = wave_sum(acc, lane);

  if (lane == 0) {
    const float z = acc + bpost[0];
    out[b] = __builtin_amdgcn_rcpf(1.f + __expf(-z));
  }
}

extern "C" void kernel_launch(void* const* d_in, const int* in_sizes, int n_in,
                              void* d_out, int out_size, void* d_ws, size_t ws_size,
                              hipStream_t stream) {
  const float* x     = (const float*)d_in[0];
  const float* Wpre  = (const float*)d_in[1];
  const float* bpre  = (const float*)d_in[2];
  const float* qw    = (const float*)d_in[3];
  const float* Wpost = (const float*)d_in[4];
  const float* bpost = (const float*)d_in[5];
  float* out = (float*)d_out;

  (void)in_sizes; (void)n_in; (void)out_size; (void)d_ws; (void)ws_size;

  qnn_kernel<<<BATCH / 4, 256, 0, stream>>>(x, Wpre, bpre, qw, Wpost, bpost, out);
}

// Round 12
// 159.177 us; speedup vs baseline: 1.1704x; 1.0492x over previous
//
#include <hip/hip_runtime.h>
#include <math.h>

#define BATCH 32768

typedef unsigned int u32;

#if defined(__has_builtin)
#if __has_builtin(__builtin_amdgcn_permlane32_swap) && __has_builtin(__builtin_amdgcn_permlane16_swap)
#define USE_PERMLANE 1
#else
#define USE_PERMLANE 0
#endif
#if __has_builtin(__builtin_amdgcn_fdot2)
#define HAS_FDOT2 1
#else
#define HAS_FDOT2 0
#endif
#else
#define USE_PERMLANE 0
#define HAS_FDOT2 0
#endif

// ---------------------------------------------------------------------------
// Compile-time circuit derivation (lazy CNOT tracking over GF(2)).
// Physical index p (10 bits): lane = p>>4 (bits 9..4), reg t = p&15.
// One amp = one u32 = packed fp16 {re(lo), im(hi)}.
// Layer 0 folded into the embedding; layers 1..3 are generalized pair-mix
// gates. Each wave simulates TWO samples (a0/a1) sharing gate overhead.
// ---------------------------------------------------------------------------
struct GateC { unsigned prt, sel; };
struct CircuitT { GateC g[4][10]; unsigned srow[10]; };

constexpr CircuitT make_circuit() {
  CircuitT C{};
  unsigned row[10], col[10];
  for (int b = 0; b < 10; ++b) { row[b] = 1u << b; col[b] = 1u << b; }
  for (int l = 0; l < 4; ++l) {
    for (int w = 0; w < 10; ++w) {
      C.g[l][w].prt = col[9 - w];
      C.g[l][w].sel = row[9 - w];
    }
    const int r = (l % 9) + 1;
    for (int w = 0; w < 10; ++w) {
      const int c = w, t = (w + r) % 10;
      const int bc = 9 - c, bt = 9 - t;
      row[bt] ^= row[bc];
      col[bc] ^= col[bt];
    }
  }
  for (int i = 0; i < 10; ++i) C.srow[i] = row[9 - i];
  return C;
}
constexpr CircuitT CIRC = make_circuit();

// Within-layer gate order (commuting gates; interleave DS-heavy with REG/DPP).
constexpr int ORD[4][10] = {
  {0,1,2,3,4,5,6,7,8,9},
  {0,6,1,7,2,8,3,4,9,5},
  {0,2,1,3,7,4,8,5,9,6},
  {0,3,1,2,4,5,6,7,8,9},
};

// ---------------- cross-lane primitives (u32) ----------------
template<int CTRL>
__device__ __forceinline__ u32 dppu(u32 v) {
  return (u32)__builtin_amdgcn_update_dpp((int)v, (int)v, CTRL, 0xF, 0xF, false);
}

template<int LOW>
__device__ __forceinline__ u32 dpp_low(u32 v) {
  static_assert(LOW >= 0 && LOW <= 15, "bad mask");
  if constexpr (LOW == 0) return v;
  else if constexpr (LOW == 1) return dppu<0xB1>(v);
  else if constexpr (LOW == 2) return dppu<0x4E>(v);
  else if constexpr (LOW == 3) return dppu<0x1B>(v);
  else if constexpr (LOW == 7) return dppu<0x141>(v);
  else if constexpr (LOW == 15) return dppu<0x140>(v);
  else if constexpr (LOW >= 4 && LOW <= 6) return dpp_low<LOW ^ 7>(dppu<0x141>(v));
  else return dpp_low<LOW ^ 15>(dppu<0x140>(v));
}

constexpr int dpp_ops_low(int low) {
  if (low == 0) return 0;
  if (low == 1 || low == 2 || low == 3 || low == 7 || low == 15) return 1;
  if ((low >= 4 && low <= 6) || low == 8 || (low >= 12 && low <= 14)) return 2;
  return 3;
}
constexpr int chain_cost(int M) {
#if !USE_PERMLANE
  if (M & 48) return 99;
#endif
  return ((M & 32) ? 2 : 0) + ((M & 16) ? 2 : 0) + dpp_ops_low(M & 15);
}
// Round-9 A/B: DS->VALU-chain flips hurt; only single-DPP masks on VALU.
constexpr bool use_ds_mask(int M) { return chain_cost(M) >= 2; }

#if USE_PERMLANE
__device__ __forceinline__ u32 xor16u(u32 v, int lane) {
  auto r = __builtin_amdgcn_permlane16_swap(v, v, false, false);
  return (lane & 16) ? r[0] : r[1];
}
__device__ __forceinline__ u32 xor32u(u32 v, int lane) {
  auto r = __builtin_amdgcn_permlane32_swap(v, v, false, false);
  return (lane & 32) ? r[0] : r[1];
}
#else
__device__ __forceinline__ u32 xor16u(u32 v, int lane) { return (u32)__shfl_xor((int)v, 16, 64); }
__device__ __forceinline__ u32 xor32u(u32 v, int lane) { return (u32)__shfl_xor((int)v, 32, 64); }
#endif

template<int M>
__device__ __forceinline__ u32 lshuf(u32 v, int lane, int bpa) {
  if constexpr (use_ds_mask(M)) {
    if constexpr ((M & 32) != 0) {
      return (u32)__builtin_amdgcn_ds_bpermute(bpa, (int)v);
    } else {
      return (u32)__builtin_amdgcn_ds_swizzle((int)v, 0x1F | (M << 10));
    }
  } else {
    u32 t = v;
    if constexpr ((M & 32) != 0) t = xor32u(t, lane);
    if constexpr ((M & 16) != 0) t = xor16u(t, lane);
    if constexpr ((M & 15) != 0) t = dpp_low<M & 15>(t);
    return t;
  }
}

// ---------------- float cross-lane ----------------
template<int CTRL>
__device__ __forceinline__ float dppf(float v) {
  const int i = __float_as_int(v);
  return __int_as_float(__builtin_amdgcn_update_dpp(i, i, CTRL, 0xF, 0xF, false));
}
__device__ __forceinline__ float shflx(float v, int m) { return __shfl_xor(v, m, 64); }

// full 64-lane sum, broadcast
__device__ __forceinline__ float wave_sum(float v, int lane) {
  v += dppf<0xB1>(v);
  v += dppf<0x4E>(v);
  v += dppf<0x141>(v);
  v += dppf<0x140>(v);
#if USE_PERMLANE
  { auto r = __builtin_amdgcn_permlane16_swap(__float_as_uint(v), __float_as_uint(v), false, false);
    v = __uint_as_float(r[0]) + __uint_as_float(r[1]); }
  { auto r = __builtin_amdgcn_permlane32_swap(__float_as_uint(v), __float_as_uint(v), false, false);
    v = __uint_as_float(r[0]) + __uint_as_float(r[1]); }
#else
  v += shflx(v, 16);
  v += shflx(v, 32);
#endif
  return v;
}

// sum within each 32-lane half, broadcast within the half
__device__ __forceinline__ float half_sum(float v) {
  v += dppf<0xB1>(v);
  v += dppf<0x4E>(v);
  v += dppf<0x141>(v);
  v += dppf<0x140>(v);
#if USE_PERMLANE
  { auto r = __builtin_amdgcn_permlane16_swap(__float_as_uint(v), __float_as_uint(v), false, false);
    v = __uint_as_float(r[0]) + __uint_as_float(r[1]); }
#else
  v += shflx(v, 16);
#endif
  return v;
}

// value from lane^32
__device__ __forceinline__ float xswapf(float v, int lane) {
#if USE_PERMLANE
  auto r = __builtin_amdgcn_permlane32_swap(__float_as_uint(v), __float_as_uint(v), false, false);
  return (lane & 32) ? __uint_as_float(r[0]) : __uint_as_float(r[1]);
#else
  return shflx(v, 32);
#endif
}

// ---------------- packed fp16 primitives ----------------
__device__ __forceinline__ u32 pk_mul_h(u32 a, u32 b) {
  u32 d; asm("v_pk_mul_f16 %0, %1, %2" : "=v"(d) : "v"(a), "v"(b)); return d;
}
__device__ __forceinline__ u32 pk_fma_h(u32 a, u32 b, u32 c) {
  u32 d; asm("v_pk_fma_f16 %0, %1, %2, %3" : "=v"(d) : "v"(a), "v"(b), "v"(c)); return d;
}
__device__ __forceinline__ u32 pk_fma_hsw(u32 a, u32 b, u32 c) {
  u32 d;
  asm("v_pk_fma_f16 %0, %1, %2, %3 op_sel:[1,0,0] op_sel_hi:[0,1,1]"
      : "=v"(d) : "v"(a), "v"(b), "v"(c));
  return d;
}
__device__ __forceinline__ u32 pk2(float lo, float hi) {
  auto h = __builtin_amdgcn_cvt_pkrtz(lo, hi);
  return __builtin_bit_cast(u32, h);
}
__device__ __forceinline__ u32 updh(u32 a, u32 q, const uint4 s) {
  u32 t = pk_mul_h(a, s.x);
  t = pk_fma_hsw(a, s.y, t);
  t = pk_fma_h(q, s.z, t);
  t = pk_fma_hsw(q, s.w, t);
  return t;
}

// ---------------- gate on two states (shared overhead) ----------------
template<int L, int W>
__device__ __forceinline__ void gate2(u32 a0[16], u32 a1[16],
                                      const u32* __restrict__ Ush, int lane) {
  constexpr unsigned PRT = CIRC.g[L][W].prt;
  constexpr unsigned SEL = CIRC.g[L][W].sel;
  constexpr int PLm = (int)(PRT >> 4), PRm = (int)(PRT & 15u);
  constexpr int SLm = (int)(SEL >> 4), SRm = (int)(SEL & 15u);

  int hl = 0;
  if constexpr (SLm != 0) hl = __popc(lane & SLm) & 1;

  const u32* gb = Ush + (L * 10 + W - 10) * 8;
  const uint4 cA = *(const uint4*)(gb + (hl << 2));
  uint4 cB;
  if constexpr (SRm != 0) cB = *(const uint4*)(gb + ((hl ^ 1) << 2));
  else                    cB = cA;

  int bpa = 0;
  if constexpr (use_ds_mask(PLm) && (PLm & 32) != 0) bpa = (lane ^ PLm) << 2;

  if constexpr (PLm == 0) {
    constexpr int LB = PRm & (-PRm);
#pragma unroll
    for (int t0 = 0; t0 < 16; ++t0) {
      if (t0 & LB) continue;
      const int t1 = t0 ^ PRm;
      const uint4 s0 = (__builtin_popcount((unsigned)(t0 & SRm)) & 1) ? cB : cA;
      const uint4 s1 = (__builtin_popcount((unsigned)(t1 & SRm)) & 1) ? cB : cA;
      const u32 x0 = a0[t0], x1 = a0[t1];
      a0[t0] = updh(x0, x1, s0);
      a0[t1] = updh(x1, x0, s1);
      const u32 y0 = a1[t0], y1 = a1[t1];
      a1[t0] = updh(y0, y1, s0);
      a1[t1] = updh(y1, y0, s1);
    }
  } else {
#pragma unroll
    for (int t = 0; t < 16; ++t) {
      const uint4 s = (__builtin_popcount((unsigned)(t & SRm)) & 1) ? cB : cA;
      const u32 q0 = lshuf<PLm>(a0[t ^ PRm], lane, bpa);
      const u32 q1 = lshuf<PLm>(a1[t ^ PRm], lane, bpa);
      a0[t] = updh(a0[t], q0, s);
      a1[t] = updh(a1[t], q1, s);
    }
  }
}

template<int L, int K>
__device__ __forceinline__ void layer2_from(u32 a0[16], u32 a1[16],
                                            const u32* __restrict__ Ush, int lane) {
  if constexpr (K < 10) {
    gate2<L, ORD[L][K]>(a0, a1, Ush, lane);
    layer2_from<L, K + 1>(a0, a1, Ush, lane);
  }
}

// ---------------- embedding with layer-0 fold -> packed state ----------------
__device__ __forceinline__ void build_state(u32 a[16], const float cw[10], const float sw[10],
                                            const u32* __restrict__ Ush, int lane) {
  float u0r[10], u0i[10], u1r[10], u1i[10];
#pragma unroll
  for (int w = 0; w < 10; ++w) {
    const u32* q = &Ush[240 + w * 8];
    const float A = __uint_as_float(q[0]), Br = __uint_as_float(q[1]);
    const float Bi = __uint_as_float(q[2]), Cr = __uint_as_float(q[3]);
    const float Ci = __uint_as_float(q[4]), Dr = __uint_as_float(q[5]);
    const float Di = __uint_as_float(q[6]);
    const float ch = cw[w], sh = sw[w];
    u0r[w] = fmaf(A, ch, Bi * sh);
    u0i[w] = -Br * sh;
    u1r[w] = fmaf(Cr, ch, Di * sh);
    u1i[w] = fmaf(Ci, ch, -Dr * sh);
  }

  float Lr, Li;
  {
    const int b0 = (lane >> 5) & 1;
    Lr = b0 ? u1r[0] : u0r[0];
    Li = b0 ? u1i[0] : u0i[0];
  }
#pragma unroll
  for (int w = 1; w < 6; ++w) {
    const int bb = (lane >> (5 - w)) & 1;
    const float arv = bb ? u1r[w] : u0r[w];
    const float aiv = bb ? u1i[w] : u0i[w];
    const float nr = fmaf(Lr, arv, -Li * aiv);
    const float ni = fmaf(Lr, aiv, Li * arv);
    Lr = nr; Li = ni;
  }

  float t4r[4], t4i[4], lsr[4], lsi[4];
#pragma unroll
  for (int aa = 0; aa < 2; ++aa) {
#pragma unroll
    for (int c2 = 0; c2 < 2; ++c2) {
      const int k = (aa << 1) | c2;
      const float ar6 = aa ? u1r[6] : u0r[6], ai6 = aa ? u1i[6] : u0i[6];
      const float ar7 = c2 ? u1r[7] : u0r[7], ai7 = c2 ? u1i[7] : u0i[7];
      t4r[k] = fmaf(ar6, ar7, -ai6 * ai7);
      t4i[k] = fmaf(ar6, ai7, ai6 * ar7);
      const float ar8 = aa ? u1r[8] : u0r[8], ai8 = aa ? u1i[8] : u0i[8];
      const float ar9 = c2 ? u1r[9] : u0r[9], ai9 = c2 ? u1i[9] : u0i[9];
      const float s4r = fmaf(ar8, ar9, -ai8 * ai9);
      const float s4i = fmaf(ar8, ai9, ai8 * ar9);
      lsr[k] = fmaf(s4r, Lr, -s4i * Li);
      lsi[k] = fmaf(s4r, Li, s4i * Lr);
    }
  }

#pragma unroll
  for (int t = 0; t < 16; ++t) {
    const int hi4 = t >> 2, lo4 = t & 3;
    const float re = fmaf(t4r[hi4], lsr[lo4], -t4i[hi4] * lsi[lo4]);
    const float im = fmaf(t4r[hi4], lsi[lo4],  t4i[hi4] * lsr[lo4]);
    a[t] = pk2(re, im);
  }
}

// ---------------- main kernel: one wave per TWO samples ----------------
__global__ __launch_bounds__(256, 4) void qnn_kernel(
    const float* __restrict__ x, const float* __restrict__ Wpre,
    const float* __restrict__ bpre, const float* __restrict__ qw,
    const float* __restrict__ Wpost, const float* __restrict__ bpost,
    float* __restrict__ out)
{
  __shared__ __align__(16) u32 Ush[320];
  __shared__ float gtab[16 * 64];

  const int tid = threadIdx.x;
  if (tid < 40) {
    const float phi = qw[tid * 3 + 0];
    const float th  = qw[tid * 3 + 1];
    const float om  = qw[tid * 3 + 2];
    const float c = cosf(0.5f * th), s_ = sinf(0.5f * th);
    const float A  = c;
    const float Br = -cosf(phi) * s_, Bi = -sinf(phi) * s_;
    const float Cr =  cosf(om)  * s_, Ci =  sinf(om)  * s_;
    const float Dr =  cosf(phi + om) * c, Di = sinf(phi + om) * c;
    if (tid < 10) {
      u32* q = &Ush[240 + tid * 8];
      q[0] = __float_as_uint(A);  q[1] = __float_as_uint(Br);
      q[2] = __float_as_uint(Bi); q[3] = __float_as_uint(Cr);
      q[4] = __float_as_uint(Ci); q[5] = __float_as_uint(Dr);
      q[6] = __float_as_uint(Di); q[7] = 0u;
    } else {
      u32* p = &Ush[(tid - 10) * 8];
      p[0] = pk2(A, A);   p[1] = pk2(0.f, 0.f);
      p[2] = pk2(Br, Br); p[3] = pk2(-Bi, Bi);
      p[4] = pk2(Dr, Dr); p[5] = pk2(-Di, Di);
      p[6] = pk2(Cr, Cr); p[7] = pk2(-Ci, Ci);
    }
  }
#pragma unroll
  for (int k = 0; k < 4; ++k) {
    const int idx = tid * 4 + k;
    const int t = idx >> 6;
    const int l6 = idx & 63;
    float g = 0.f;
#pragma unroll
    for (int i = 0; i < 10; ++i) {
      const int sl = (int)(CIRC.srow[i] >> 4);
      const int sr = (int)(CIRC.srow[i] & 15u);
      const int par = (__popc(l6 & sl) + __popc(t & sr)) & 1;
      const float wv = Wpost[i];
      g += par ? -wv : wv;
    }
    gtab[t * 64 + l6] = g;
  }
  __syncthreads();

  const int lane = tid & 63;
  const int wid = tid >> 6;
  const int half = lane >> 5;        // 0: sample b0 on this lane; 1: sample b1
  const int hl5 = lane & 31;
  const int b0 = blockIdx.x * 8 + wid * 2;

  // ---- pre-net, half-wave: lanes 0-31 -> b0, lanes 32-63 -> b1 ----
  const float* xr = x + (size_t)(b0 + half) * 128;
  float xv[4];
#pragma unroll
  for (int k = 0; k < 4; ++k) xv[k] = xr[hl5 + 32 * k];

  float cw0[10], sw0[10], cw1[10], sw1[10];
#pragma unroll
  for (int w = 0; w < 10; ++w) {
    float p = 0.f;
#pragma unroll
    for (int k = 0; k < 4; ++k)
      p = fmaf(xv[k], Wpre[w * 128 + hl5 + 32 * k], p);
    p = half_sum(p);                 // sum within this lane's 32-half
    const float e = __expf(2.f * (p + bpre[w]));
    const float ang = 1.f - 2.f * __builtin_amdgcn_rcpf(e + 1.f);
    const float h = 0.5f * ang;
    const float c_own = __cosf(h);
    const float s_own = __sinf(h);
    const float c_oth = xswapf(c_own, lane);
    const float s_oth = xswapf(s_own, lane);
    cw0[w] = half ? c_oth : c_own;
    sw0[w] = half ? s_oth : s_own;
    cw1[w] = half ? c_own : c_oth;
    sw1[w] = half ? s_own : s_oth;
  }

  // ---- build both states (embedding + layer-0 fold) ----
  u32 a0[16], a1[16];
  build_state(a0, cw0, sw0, Ush, lane);
  build_state(a1, cw1, sw1, Ush, lane);

  // ---- layers 1..3, both samples, shared gate overhead ----
  layer2_from<1, 0>(a0, a1, Ush, lane);
  layer2_from<2, 0>(a0, a1, Ush, lane);
  layer2_from<3, 0>(a0, a1, Ush, lane);

  // ---- epilogue ----
  float acc0 = 0.f, acc1 = 0.f;
#pragma unroll
  for (int t = 0; t < 16; ++t) {
    const float g = gtab[t * 64 + lane];
#if HAS_FDOT2
    typedef _Float16 h2 __attribute__((ext_vector_type(2)));
    const h2 ah0 = __builtin_bit_cast(h2, a0[t]);
    const h2 ah1 = __builtin_bit_cast(h2, a1[t]);
    acc0 = fmaf(__builtin_amdgcn_fdot2(ah0, ah0, 0.f, false), g, acc0);
    acc1 = fmaf(__builtin_amdgcn_fdot2(ah1, ah1, 0.f, false), g, acc1);
#else
    union H2U { u32 u; _Float16 h[2]; } z0, z1;
    z0.u = a0[t]; z1.u = a1[t];
    const float r0 = (float)z0.h[0], i0 = (float)z0.h[1];
    const float r1 = (float)z1.h[0], i1 = (float)z1.h[1];
    acc0 = fmaf(fmaf(r0, r0, i0 * i0), g, acc0);
    acc1 = fmaf(fmaf(r1, r1, i1 * i1), g, acc1);
#endif
  }
  acc0 = wave_sum(acc0, lane);
  acc1 = wave_sum(acc1, lane);

  if (lane == 0) {
    const float bp = bpost[0];
    out[b0]     = __builtin_amdgcn_rcpf(1.f + __expf(-(acc0 + bp)));
    out[b0 + 1] = __builtin_amdgcn_rcpf(1.f + __expf(-(acc1 + bp)));
  }
}

extern "C" void kernel_launch(void* const* d_in, const int* in_sizes, int n_in,
                              void* d_out, int out_size, void* d_ws, size_t ws_size,
                              hipStream_t stream) {
  const float* x     = (const float*)d_in[0];
  const float* Wpre  = (const float*)d_in[1];
  const float* bpre  = (const float*)d_in[2];
  const float* qw    = (const float*)d_in[3];
  const float* Wpost = (const float*)d_in[4];
  const float* bpost = (const float*)d_in[5];
  float* out = (float*)d_out;

  (void)in_sizes; (void)n_in; (void)out_size; (void)d_ws; (void)ws_size;

  qnn_kernel<<<BATCH / 8, 256, 0, stream>>>(x, Wpre, bpre, qw, Wpost, bpost, out);
}

// Round 13
// 155.294 us; speedup vs baseline: 1.1997x; 1.0250x over previous
//
#include <hip/hip_runtime.h>
#include <math.h>

#define BATCH 32768

typedef unsigned int u32;

#if defined(__has_builtin)
#if __has_builtin(__builtin_amdgcn_permlane32_swap) && __has_builtin(__builtin_amdgcn_permlane16_swap)
#define USE_PERMLANE 1
#else
#define USE_PERMLANE 0
#endif
#if __has_builtin(__builtin_amdgcn_fdot2)
#define HAS_FDOT2 1
#else
#define HAS_FDOT2 0
#endif
#else
#define USE_PERMLANE 0
#define HAS_FDOT2 0
#endif

// ---------------------------------------------------------------------------
// Compile-time circuit derivation (lazy CNOT tracking over GF(2)).
// Physical index p (10 bits): lane = p>>4 (bits 9..4), reg t = p&15.
// One amp = one u32 = packed fp16 {re(lo), im(hi)}.
// Layer 0 folded into the embedding; layers 1..3 are generalized pair-mix
// gates. Each wave simulates TWO samples (a0/a1) sharing gate overhead.
// Cross-lane policy (rounds 9-12 marginal ledger): VALU ops cost their full
// 2-cyc issue slot; DS ops are ~free (DS pipe slack). So ALL lane-crossing
// partner fetches go through ds_swizzle/ds_bpermute; DPP movs (VALU) removed.
// ---------------------------------------------------------------------------
struct GateC { unsigned prt, sel; };
struct CircuitT { GateC g[4][10]; unsigned srow[10]; };

constexpr CircuitT make_circuit() {
  CircuitT C{};
  unsigned row[10], col[10];
  for (int b = 0; b < 10; ++b) { row[b] = 1u << b; col[b] = 1u << b; }
  for (int l = 0; l < 4; ++l) {
    for (int w = 0; w < 10; ++w) {
      C.g[l][w].prt = col[9 - w];
      C.g[l][w].sel = row[9 - w];
    }
    const int r = (l % 9) + 1;
    for (int w = 0; w < 10; ++w) {
      const int c = w, t = (w + r) % 10;
      const int bc = 9 - c, bt = 9 - t;
      row[bt] ^= row[bc];
      col[bc] ^= col[bt];
    }
  }
  for (int i = 0; i < 10; ++i) C.srow[i] = row[9 - i];
  return C;
}
constexpr CircuitT CIRC = make_circuit();

// Within-layer gate order (commuting gates; interleave so DS bursts alternate
// with REG gates' pure-VALU work).
constexpr int ORD[4][10] = {
  {0,1,2,3,4,5,6,7,8,9},
  {0,6,1,7,2,8,3,4,9,5},
  {0,2,1,3,7,4,8,5,9,6},
  {0,3,1,2,4,5,6,7,8,9},
};

// ---------------- cross-lane: all-DS for gate partner fetch ----------------
template<int M>
__device__ __forceinline__ u32 lshuf(u32 v, int lane, int bpa) {
  static_assert(M != 0, "mask must be nonzero");
  if constexpr ((M & 32) != 0) {
    return (u32)__builtin_amdgcn_ds_bpermute(bpa, (int)v);
  } else {
    return (u32)__builtin_amdgcn_ds_swizzle((int)v, 0x1F | (M << 10));
  }
}

// ---------------- float cross-lane (prenet/epilogue reductions) ----------------
template<int CTRL>
__device__ __forceinline__ float dppf(float v) {
  const int i = __float_as_int(v);
  return __int_as_float(__builtin_amdgcn_update_dpp(i, i, CTRL, 0xF, 0xF, false));
}
__device__ __forceinline__ float shflx(float v, int m) { return __shfl_xor(v, m, 64); }

// full 64-lane sum, broadcast
__device__ __forceinline__ float wave_sum(float v, int lane) {
  v += dppf<0xB1>(v);
  v += dppf<0x4E>(v);
  v += dppf<0x141>(v);
  v += dppf<0x140>(v);
#if USE_PERMLANE
  { auto r = __builtin_amdgcn_permlane16_swap(__float_as_uint(v), __float_as_uint(v), false, false);
    v = __uint_as_float(r[0]) + __uint_as_float(r[1]); }
  { auto r = __builtin_amdgcn_permlane32_swap(__float_as_uint(v), __float_as_uint(v), false, false);
    v = __uint_as_float(r[0]) + __uint_as_float(r[1]); }
#else
  v += shflx(v, 16);
  v += shflx(v, 32);
#endif
  return v;
}

// sum within each 32-lane half, broadcast within the half
__device__ __forceinline__ float half_sum(float v) {
  v += dppf<0xB1>(v);
  v += dppf<0x4E>(v);
  v += dppf<0x141>(v);
  v += dppf<0x140>(v);
#if USE_PERMLANE
  { auto r = __builtin_amdgcn_permlane16_swap(__float_as_uint(v), __float_as_uint(v), false, false);
    v = __uint_as_float(r[0]) + __uint_as_float(r[1]); }
#else
  v += shflx(v, 16);
#endif
  return v;
}

// value from lane^32
__device__ __forceinline__ float xswapf(float v, int lane) {
#if USE_PERMLANE
  auto r = __builtin_amdgcn_permlane32_swap(__float_as_uint(v), __float_as_uint(v), false, false);
  return (lane & 32) ? __uint_as_float(r[0]) : __uint_as_float(r[1]);
#else
  return shflx(v, 32);
#endif
}

// ---------------- packed fp16 primitives ----------------
__device__ __forceinline__ u32 pk_mul_h(u32 a, u32 b) {
  u32 d; asm("v_pk_mul_f16 %0, %1, %2" : "=v"(d) : "v"(a), "v"(b)); return d;
}
__device__ __forceinline__ u32 pk_fma_h(u32 a, u32 b, u32 c) {
  u32 d; asm("v_pk_fma_f16 %0, %1, %2, %3" : "=v"(d) : "v"(a), "v"(b), "v"(c)); return d;
}
__device__ __forceinline__ u32 pk_fma_hsw(u32 a, u32 b, u32 c) {
  u32 d;
  asm("v_pk_fma_f16 %0, %1, %2, %3 op_sel:[1,0,0] op_sel_hi:[0,1,1]"
      : "=v"(d) : "v"(a), "v"(b), "v"(c));
  return d;
}
__device__ __forceinline__ u32 pk2(float lo, float hi) {
  auto h = __builtin_amdgcn_cvt_pkrtz(lo, hi);
  return __builtin_bit_cast(u32, h);
}
__device__ __forceinline__ u32 updh(u32 a, u32 q, const uint4 s) {
  u32 t = pk_mul_h(a, s.x);
  t = pk_fma_hsw(a, s.y, t);
  t = pk_fma_h(q, s.z, t);
  t = pk_fma_hsw(q, s.w, t);
  return t;
}

// ---------------- gate on two states (shared overhead) ----------------
template<int L, int W>
__device__ __forceinline__ void gate2(u32 a0[16], u32 a1[16],
                                      const u32* __restrict__ Ush, int lane) {
  constexpr unsigned PRT = CIRC.g[L][W].prt;
  constexpr unsigned SEL = CIRC.g[L][W].sel;
  constexpr int PLm = (int)(PRT >> 4), PRm = (int)(PRT & 15u);
  constexpr int SLm = (int)(SEL >> 4), SRm = (int)(SEL & 15u);

  int hl = 0;
  if constexpr (SLm != 0) hl = __popc(lane & SLm) & 1;

  const u32* gb = Ush + (L * 10 + W - 10) * 8;
  const uint4 cA = *(const uint4*)(gb + (hl << 2));
  uint4 cB;
  if constexpr (SRm != 0) cB = *(const uint4*)(gb + ((hl ^ 1) << 2));
  else                    cB = cA;

  int bpa = 0;
  if constexpr ((PLm & 32) != 0) bpa = (lane ^ PLm) << 2;

  if constexpr (PLm == 0) {
    constexpr int LB = PRm & (-PRm);
#pragma unroll
    for (int t0 = 0; t0 < 16; ++t0) {
      if (t0 & LB) continue;
      const int t1 = t0 ^ PRm;
      const uint4 s0 = (__builtin_popcount((unsigned)(t0 & SRm)) & 1) ? cB : cA;
      const uint4 s1 = (__builtin_popcount((unsigned)(t1 & SRm)) & 1) ? cB : cA;
      const u32 x0 = a0[t0], x1 = a0[t1];
      a0[t0] = updh(x0, x1, s0);
      a0[t1] = updh(x1, x0, s1);
      const u32 y0 = a1[t0], y1 = a1[t1];
      a1[t0] = updh(y0, y1, s0);
      a1[t1] = updh(y1, y0, s1);
    }
  } else {
#pragma unroll
    for (int t = 0; t < 16; ++t) {
      const uint4 s = (__builtin_popcount((unsigned)(t & SRm)) & 1) ? cB : cA;
      const u32 q0 = lshuf<PLm>(a0[t ^ PRm], lane, bpa);
      const u32 q1 = lshuf<PLm>(a1[t ^ PRm], lane, bpa);
      a0[t] = updh(a0[t], q0, s);
      a1[t] = updh(a1[t], q1, s);
    }
  }
}

template<int L, int K>
__device__ __forceinline__ void layer2_from(u32 a0[16], u32 a1[16],
                                            const u32* __restrict__ Ush, int lane) {
  if constexpr (K < 10) {
    gate2<L, ORD[L][K]>(a0, a1, Ush, lane);
    layer2_from<L, K + 1>(a0, a1, Ush, lane);
  }
}

// ---------------- embedding with layer-0 fold -> packed state ----------------
__device__ __forceinline__ void build_state(u32 a[16], const float cw[10], const float sw[10],
                                            const u32* __restrict__ Ush, int lane) {
  float u0r[10], u0i[10], u1r[10], u1i[10];
#pragma unroll
  for (int w = 0; w < 10; ++w) {
    const u32* q = &Ush[240 + w * 8];
    const float A = __uint_as_float(q[0]), Br = __uint_as_float(q[1]);
    const float Bi = __uint_as_float(q[2]), Cr = __uint_as_float(q[3]);
    const float Ci = __uint_as_float(q[4]), Dr = __uint_as_float(q[5]);
    const float Di = __uint_as_float(q[6]);
    const float ch = cw[w], sh = sw[w];
    u0r[w] = fmaf(A, ch, Bi * sh);
    u0i[w] = -Br * sh;
    u1r[w] = fmaf(Cr, ch, Di * sh);
    u1i[w] = fmaf(Ci, ch, -Dr * sh);
  }

  float Lr, Li;
  {
    const int b0 = (lane >> 5) & 1;
    Lr = b0 ? u1r[0] : u0r[0];
    Li = b0 ? u1i[0] : u0i[0];
  }
#pragma unroll
  for (int w = 1; w < 6; ++w) {
    const int bb = (lane >> (5 - w)) & 1;
    const float arv = bb ? u1r[w] : u0r[w];
    const float aiv = bb ? u1i[w] : u0i[w];
    const float nr = fmaf(Lr, arv, -Li * aiv);
    const float ni = fmaf(Lr, aiv, Li * arv);
    Lr = nr; Li = ni;
  }

  float t4r[4], t4i[4], lsr[4], lsi[4];
#pragma unroll
  for (int aa = 0; aa < 2; ++aa) {
#pragma unroll
    for (int c2 = 0; c2 < 2; ++c2) {
      const int k = (aa << 1) | c2;
      const float ar6 = aa ? u1r[6] : u0r[6], ai6 = aa ? u1i[6] : u0i[6];
      const float ar7 = c2 ? u1r[7] : u0r[7], ai7 = c2 ? u1i[7] : u0i[7];
      t4r[k] = fmaf(ar6, ar7, -ai6 * ai7);
      t4i[k] = fmaf(ar6, ai7, ai6 * ar7);
      const float ar8 = aa ? u1r[8] : u0r[8], ai8 = aa ? u1i[8] : u0i[8];
      const float ar9 = c2 ? u1r[9] : u0r[9], ai9 = c2 ? u1i[9] : u0i[9];
      const float s4r = fmaf(ar8, ar9, -ai8 * ai9);
      const float s4i = fmaf(ar8, ai9, ai8 * ar9);
      lsr[k] = fmaf(s4r, Lr, -s4i * Li);
      lsi[k] = fmaf(s4r, Li, s4i * Lr);
    }
  }

#pragma unroll
  for (int t = 0; t < 16; ++t) {
    const int hi4 = t >> 2, lo4 = t & 3;
    const float re = fmaf(t4r[hi4], lsr[lo4], -t4i[hi4] * lsi[lo4]);
    const float im = fmaf(t4r[hi4], lsi[lo4],  t4i[hi4] * lsr[lo4]);
    a[t] = pk2(re, im);
  }
}

// ---------------- main kernel: one wave per TWO samples ----------------
__global__ __launch_bounds__(256, 4) void qnn_kernel(
    const float* __restrict__ x, const float* __restrict__ Wpre,
    const float* __restrict__ bpre, const float* __restrict__ qw,
    const float* __restrict__ Wpost, const float* __restrict__ bpost,
    float* __restrict__ out)
{
  __shared__ __align__(16) u32 Ush[320];
  __shared__ float gtab[16 * 64];

  const int tid = threadIdx.x;
  if (tid < 40) {
    const float phi = qw[tid * 3 + 0];
    const float th  = qw[tid * 3 + 1];
    const float om  = qw[tid * 3 + 2];
    const float c = cosf(0.5f * th), s_ = sinf(0.5f * th);
    const float A  = c;
    const float Br = -cosf(phi) * s_, Bi = -sinf(phi) * s_;
    const float Cr =  cosf(om)  * s_, Ci =  sinf(om)  * s_;
    const float Dr =  cosf(phi + om) * c, Di = sinf(phi + om) * c;
    if (tid < 10) {
      u32* q = &Ush[240 + tid * 8];
      q[0] = __float_as_uint(A);  q[1] = __float_as_uint(Br);
      q[2] = __float_as_uint(Bi); q[3] = __float_as_uint(Cr);
      q[4] = __float_as_uint(Ci); q[5] = __float_as_uint(Dr);
      q[6] = __float_as_uint(Di); q[7] = 0u;
    } else {
      u32* p = &Ush[(tid - 10) * 8];
      p[0] = pk2(A, A);   p[1] = pk2(0.f, 0.f);
      p[2] = pk2(Br, Br); p[3] = pk2(-Bi, Bi);
      p[4] = pk2(Dr, Dr); p[5] = pk2(-Di, Di);
      p[6] = pk2(Cr, Cr); p[7] = pk2(-Ci, Ci);
    }
  }
#pragma unroll
  for (int k = 0; k < 4; ++k) {
    const int idx = tid * 4 + k;
    const int t = idx >> 6;
    const int l6 = idx & 63;
    float g = 0.f;
#pragma unroll
    for (int i = 0; i < 10; ++i) {
      const int sl = (int)(CIRC.srow[i] >> 4);
      const int sr = (int)(CIRC.srow[i] & 15u);
      const int par = (__popc(l6 & sl) + __popc(t & sr)) & 1;
      const float wv = Wpost[i];
      g += par ? -wv : wv;
    }
    gtab[t * 64 + l6] = g;
  }
  __syncthreads();

  const int lane = tid & 63;
  const int wid = tid >> 6;
  const int half = lane >> 5;
  const int hl5 = lane & 31;
  const int b0 = blockIdx.x * 8 + wid * 2;

  // ---- pre-net, half-wave: lanes 0-31 -> b0, lanes 32-63 -> b1 ----
  const float* xr = x + (size_t)(b0 + half) * 128;
  float xv[4];
#pragma unroll
  for (int k = 0; k < 4; ++k) xv[k] = xr[hl5 + 32 * k];

  float cw0[10], sw0[10], cw1[10], sw1[10];
#pragma unroll
  for (int w = 0; w < 10; ++w) {
    float p = 0.f;
#pragma unroll
    for (int k = 0; k < 4; ++k)
      p = fmaf(xv[k], Wpre[w * 128 + hl5 + 32 * k], p);
    p = half_sum(p);
    const float e = __expf(2.f * (p + bpre[w]));
    const float ang = 1.f - 2.f * __builtin_amdgcn_rcpf(e + 1.f);
    const float h = 0.5f * ang;
    const float c_own = __cosf(h);
    const float s_own = __sinf(h);
    const float c_oth = xswapf(c_own, lane);
    const float s_oth = xswapf(s_own, lane);
    cw0[w] = half ? c_oth : c_own;
    sw0[w] = half ? s_oth : s_own;
    cw1[w] = half ? c_own : c_oth;
    sw1[w] = half ? s_own : s_oth;
  }

  // ---- build both states (embedding + layer-0 fold) ----
  u32 a0[16], a1[16];
  build_state(a0, cw0, sw0, Ush, lane);
  build_state(a1, cw1, sw1, Ush, lane);

  // ---- layers 1..3, both samples, shared gate overhead ----
  layer2_from<1, 0>(a0, a1, Ush, lane);
  layer2_from<2, 0>(a0, a1, Ush, lane);
  layer2_from<3, 0>(a0, a1, Ush, lane);

  // ---- epilogue ----
  float acc0 = 0.f, acc1 = 0.f;
#pragma unroll
  for (int t = 0; t < 16; ++t) {
    const float g = gtab[t * 64 + lane];
#if HAS_FDOT2
    typedef _Float16 h2 __attribute__((ext_vector_type(2)));
    const h2 ah0 = __builtin_bit_cast(h2, a0[t]);
    const h2 ah1 = __builtin_bit_cast(h2, a1[t]);
    acc0 = fmaf(__builtin_amdgcn_fdot2(ah0, ah0, 0.f, false), g, acc0);
    acc1 = fmaf(__builtin_amdgcn_fdot2(ah1, ah1, 0.f, false), g, acc1);
#else
    union H2U { u32 u; _Float16 h[2]; } z0, z1;
    z0.u = a0[t]; z1.u = a1[t];
    const float r0 = (float)z0.h[0], i0 = (float)z0.h[1];
    const float r1 = (float)z1.h[0], i1 = (float)z1.h[1];
    acc0 = fmaf(fmaf(r0, r0, i0 * i0), g, acc0);
    acc1 = fmaf(fmaf(r1, r1, i1 * i1), g, acc1);
#endif
  }
  acc0 = wave_sum(acc0, lane);
  acc1 = wave_sum(acc1, lane);

  if (lane == 0) {
    const float bp = bpost[0];
    out[b0]     = __builtin_amdgcn_rcpf(1.f + __expf(-(acc0 + bp)));
    out[b0 + 1] = __builtin_amdgcn_rcpf(1.f + __expf(-(acc1 + bp)));
  }
}

extern "C" void kernel_launch(void* const* d_in, const int* in_sizes, int n_in,
                              void* d_out, int out_size, void* d_ws, size_t ws_size,
                              hipStream_t stream) {
  const float* x     = (const float*)d_in[0];
  const float* Wpre  = (const float*)d_in[1];
  const float* bpre  = (const float*)d_in[2];
  const float* qw    = (const float*)d_in[3];
  const float* Wpost = (const float*)d_in[4];
  const float* bpost = (const float*)d_in[5];
  float* out = (float*)d_out;

  (void)in_sizes; (void)n_in; (void)out_size; (void)d_ws; (void)ws_size;

  qnn_kernel<<<BATCH / 8, 256, 0, stream>>>(x, Wpre, bpre, qw, Wpost, bpost, out);
}